// Round 4
// baseline (772.031 us; speedup 1.0000x reference)
//
#include <hip/hip_runtime.h>
#include <hip/hip_bf16.h>
#include <math.h>

// Problem constants
#define BB 2
#define TT 2048
#define DD 1024
#define HH 16
#define DK 64
#define KT 128            // keys per attention tile

typedef __attribute__((ext_vector_type(8))) short bf16x8;
typedef __attribute__((ext_vector_type(4))) float f32x4;

static __device__ __forceinline__ short f2bf(float f) {
    __hip_bfloat16 h = __float2bfloat16(f);
    union { __hip_bfloat16 h; short s; } u; u.h = h; return u.s;
}
static __device__ __forceinline__ float bf2f(short s) {
    union { short s; __hip_bfloat16 h; } u; u.s = s; return __bfloat162float(u.h);
}
static __device__ __forceinline__ int packbf(float a, float b) {
    unsigned int ua = (unsigned short)f2bf(a);
    unsigned int ub = (unsigned short)f2bf(b);
    return (int)(ua | (ub << 16));
}

// ---------------------------------------------------------------------------
// Split-bf16 MFMA GEMM: C[M,N] = A[M,K] @ Bw[N,K]^T (+bias). (unchanged R2)
// ---------------------------------------------------------------------------
__global__ __launch_bounds__(256) void gemm_mfma_nt(
    const float* __restrict__ A, const float* __restrict__ Bw,
    const float* __restrict__ bias, float* __restrict__ C,
    int M, int N, int K, int hasBias)
{
    __shared__ short Ah[64][40];
    __shared__ short Al[64][40];
    __shared__ short Bh[128][40];
    __shared__ short Bl[128][40];

    const int t    = threadIdx.x;
    const int m0   = blockIdx.y * 64;
    const int n0   = blockIdx.x * 128;
    const int lane = t & 63;
    const int w    = t >> 6;
    const int wm   = w >> 1;
    const int wn   = w & 1;
    const int l15  = lane & 15;
    const int quad = lane >> 4;

    const int ar = t >> 2, ac = (t & 3) * 8;
    const int br = t >> 1, bc = (t & 1) * 16;

    const float* Aptr = A + (size_t)(m0 + ar) * K + ac;
    const float* Bptr = Bw + (size_t)(n0 + br) * K + bc;

    f32x4 acc[2][4];
#pragma unroll
    for (int i = 0; i < 2; ++i)
#pragma unroll
        for (int j = 0; j < 4; ++j) acc[i][j] = (f32x4)0.f;

    for (int k0 = 0; k0 < K; k0 += 32) {
        float4 a0 = *(const float4*)(Aptr + k0);
        float4 a1 = *(const float4*)(Aptr + k0 + 4);
        float4 b0 = *(const float4*)(Bptr + k0);
        float4 b1 = *(const float4*)(Bptr + k0 + 4);
        float4 b2 = *(const float4*)(Bptr + k0 + 8);
        float4 b3 = *(const float4*)(Bptr + k0 + 12);

        __syncthreads();
        {
            union { short s[8]; int4 v; } ph, pl;
            float va[8] = {a0.x, a0.y, a0.z, a0.w, a1.x, a1.y, a1.z, a1.w};
#pragma unroll
            for (int j = 0; j < 8; ++j) {
                short h = f2bf(va[j]);
                ph.s[j] = h;
                pl.s[j] = f2bf(va[j] - bf2f(h));
            }
            *(int4*)&Ah[ar][ac] = ph.v;
            *(int4*)&Al[ar][ac] = pl.v;
        }
        {
            union { short s[8]; int4 v; } ph, pl;
            float vb[8] = {b0.x, b0.y, b0.z, b0.w, b1.x, b1.y, b1.z, b1.w};
#pragma unroll
            for (int j = 0; j < 8; ++j) {
                short h = f2bf(vb[j]);
                ph.s[j] = h;
                pl.s[j] = f2bf(vb[j] - bf2f(h));
            }
            *(int4*)&Bh[br][bc] = ph.v;
            *(int4*)&Bl[br][bc] = pl.v;
        }
        {
            union { short s[8]; int4 v; } ph, pl;
            float vb[8] = {b2.x, b2.y, b2.z, b2.w, b3.x, b3.y, b3.z, b3.w};
#pragma unroll
            for (int j = 0; j < 8; ++j) {
                short h = f2bf(vb[j]);
                ph.s[j] = h;
                pl.s[j] = f2bf(vb[j] - bf2f(h));
            }
            *(int4*)&Bh[br][bc + 8] = ph.v;
            *(int4*)&Bl[br][bc + 8] = pl.v;
        }
        __syncthreads();

        bf16x8 ah[2], al[2], bh[4], bl[4];
#pragma unroll
        for (int tm = 0; tm < 2; ++tm) {
            ah[tm] = *(const bf16x8*)&Ah[wm * 32 + tm * 16 + l15][quad * 8];
            al[tm] = *(const bf16x8*)&Al[wm * 32 + tm * 16 + l15][quad * 8];
        }
#pragma unroll
        for (int tn = 0; tn < 4; ++tn) {
            bh[tn] = *(const bf16x8*)&Bh[wn * 64 + tn * 16 + l15][quad * 8];
            bl[tn] = *(const bf16x8*)&Bl[wn * 64 + tn * 16 + l15][quad * 8];
        }
#pragma unroll
        for (int tm = 0; tm < 2; ++tm)
#pragma unroll
            for (int tn = 0; tn < 4; ++tn) {
                acc[tm][tn] = __builtin_amdgcn_mfma_f32_16x16x32_bf16(
                    ah[tm], bh[tn], acc[tm][tn], 0, 0, 0);
                acc[tm][tn] = __builtin_amdgcn_mfma_f32_16x16x32_bf16(
                    ah[tm], bl[tn], acc[tm][tn], 0, 0, 0);
                acc[tm][tn] = __builtin_amdgcn_mfma_f32_16x16x32_bf16(
                    al[tm], bh[tn], acc[tm][tn], 0, 0, 0);
            }
    }

#pragma unroll
    for (int tm = 0; tm < 2; ++tm)
#pragma unroll
        for (int tn = 0; tn < 4; ++tn) {
            const int col  = n0 + wn * 64 + tn * 16 + l15;
            const float bv = hasBias ? bias[col] : 0.f;
            const int rowb = m0 + wm * 32 + tm * 16 + quad * 4;
#pragma unroll
            for (int r = 0; r < 4; ++r)
                C[(size_t)(rowb + r) * N + col] = acc[tm][tn][r] + bv;
        }
}

// ---------------------------------------------------------------------------
// Normalize each 64-wide head segment; emit hi/lo split bf16 at [b][h][t][dk].
// ---------------------------------------------------------------------------
__global__ __launch_bounds__(256) void normsplit_kernel(
    const float* __restrict__ X, short* __restrict__ Hi, short* __restrict__ Lo)
{
    const int seg  = blockIdx.x * 4 + (threadIdx.x >> 6);
    const int lane = threadIdx.x & 63;
    const int row  = seg >> 4;   // b*T + t
    const int h    = seg & 15;
    float v = X[(size_t)row * DD + h * DK + lane];
    float s = v * v;
    s += __shfl_xor(s, 1);
    s += __shfl_xor(s, 2);
    s += __shfl_xor(s, 4);
    s += __shfl_xor(s, 8);
    s += __shfl_xor(s, 16);
    s += __shfl_xor(s, 32);
    float n = sqrtf(s);
    float vn = v / fmaxf(n, 1e-12f);
    const int b  = row >> 11;
    const int tt = row & 2047;
    size_t o = ((size_t)(b * HH + h) * TT + tt) * DK + lane;
    short hv = f2bf(vn);
    Hi[o] = hv;
    Lo[o] = f2bf(vn - bf2f(hv));
}

// ---------------------------------------------------------------------------
// V -> bf16 transposed [b][h][d][T].
// ---------------------------------------------------------------------------
__global__ __launch_bounds__(256) void vtrans_kernel(
    const float* __restrict__ V0, short* __restrict__ Vt)
{
    __shared__ short Vtmp[64][72];
    const int t  = threadIdx.x;
    const int t0 = blockIdx.x * 64;
    const int h  = blockIdx.y;
    const int b  = blockIdx.z;

    {
        const int i  = t >> 2;            // token row 0..63
        const int jc = (t & 3) * 16;      // dim chunk
        const float* src = V0 + (size_t)(b * TT + t0 + i) * DD + h * DK + jc;
#pragma unroll
        for (int c = 0; c < 4; ++c) {
            float4 v = *(const float4*)(src + c * 4);
            Vtmp[jc + c * 4 + 0][i] = f2bf(v.x);
            Vtmp[jc + c * 4 + 1][i] = f2bf(v.y);
            Vtmp[jc + c * 4 + 2][i] = f2bf(v.z);
            Vtmp[jc + c * 4 + 3][i] = f2bf(v.w);
        }
    }
    __syncthreads();
    {
        const int d  = t >> 2;
        const int kc = (t & 3) * 16;
        short* dst = Vt + ((size_t)((b * HH + h) * DK + d)) * TT + t0 + kc;
        *(int4*)(dst)     = *(const int4*)&Vtmp[d][kc];
        *(int4*)(dst + 8) = *(const int4*)&Vtmp[d][kc + 8];
    }
}

// ---------------------------------------------------------------------------
// MFMA angular attention. Grid (T/64, H, B), 256 threads (4 waves).
// Block: 64 queries; key tiles of 128; wave w owns keys [w*32, w*32+32).
// S^T = K·Q^T via 16x16x32 MFMA (split hi/lo, 3 products). Transform in
// C-regs. W pairs -> per-wave LDS region -> A-frags for PV MFMA.
// Each wave accumulates partial O[64q x 64d] over its keys; cross-wave
// reduction through LDS at the end. Rowsum kept fp32 in registers.
// __launch_bounds__(256,1): R3's (256,2) forced a 128-VGPR cap -> scratch
// spills (1.9 GB WRITE_SIZE). Let the allocator keep ~230 arch regs.
// ---------------------------------------------------------------------------
__global__ __launch_bounds__(256, 1) void attn_kernel(
    const short* __restrict__ Qhi, const short* __restrict__ Qlo,
    const short* __restrict__ Khi_g, const short* __restrict__ Klo_g,
    const short* __restrict__ Vt_g, float* __restrict__ Oa)
{
    __shared__ union {
        short k[2][128][72];          // [hi/lo][key][dk]
        float obuf[64][68];           // epilogue O reduction
    } U;
    __shared__ short Vts[64][136];    // [d][key]
    __shared__ int   Wls[4][64][20];  // per-wave W pairs: [w][q][keypair]
    __shared__ float Rbuf[4][64];
    __shared__ float Rfin[64];

    const int t    = threadIdx.x;
    const int lane = t & 63;
    const int w    = t >> 6;
    const int l15  = lane & 15;
    const int quad = lane >> 4;
    const int q0   = blockIdx.x * 64;
    const int h    = blockIdx.y;
    const int b    = blockIdx.z;
    const size_t bh = (size_t)(b * HH + h);

    // hoist Q B-frags (q = 16*t4 + l15, k = s*32 + quad*8)
    bf16x8 qf[4][2][2];
    {
        const short* qh = Qhi + (bh * TT + q0) * DK;
        const short* ql = Qlo + (bh * TT + q0) * DK;
#pragma unroll
        for (int t4 = 0; t4 < 4; ++t4)
#pragma unroll
            for (int s = 0; s < 2; ++s) {
                size_t off = (size_t)(16 * t4 + l15) * DK + s * 32 + quad * 8;
                qf[t4][s][0] = *(const bf16x8*)(qh + off);
                qf[t4][s][1] = *(const bf16x8*)(ql + off);
            }
    }

    f32x4 acc[4][4];   // [qt][nd] partial O
#pragma unroll
    for (int i = 0; i < 4; ++i)
#pragma unroll
        for (int j = 0; j < 4; ++j) acc[i][j] = (f32x4)0.f;
    float partial[4] = {0.f, 0.f, 0.f, 0.f};

    const short* kh_g = Khi_g + bh * TT * DK;
    const short* kl_g = Klo_g + bh * TT * DK;
    const short* vt_g = Vt_g + bh * (size_t)DK * TT;

    const int srow = t >> 1;          // K stage row 0..127
    const int scol = (t & 1) * 32;    // shorts
    const int vrow = t >> 2;          // V stage d 0..63
    const int vcol = (t & 3) * 32;    // shorts

    for (int k0 = 0; k0 < TT; k0 += KT) {
        int4 kh[4], kl[4], vv[4];
        {
            const short* kp = kh_g + (size_t)(k0 + srow) * DK + scol;
            const short* lp = kl_g + (size_t)(k0 + srow) * DK + scol;
            const short* vp = vt_g + (size_t)vrow * TT + k0 + vcol;
#pragma unroll
            for (int c = 0; c < 4; ++c) {
                kh[c] = *(const int4*)(kp + c * 8);
                kl[c] = *(const int4*)(lp + c * 8);
                vv[c] = *(const int4*)(vp + c * 8);
            }
        }
        __syncthreads();
#pragma unroll
        for (int c = 0; c < 4; ++c) {
            *(int4*)&U.k[0][srow][scol + c * 8] = kh[c];
            *(int4*)&U.k[1][srow][scol + c * 8] = kl[c];
            *(int4*)&Vts[vrow][vcol + c * 8]    = vv[c];
        }
        __syncthreads();

        // S^T tiles + transform; wave keys [w*32, w*32+32)
#pragma unroll
        for (int mt = 0; mt < 2; ++mt) {
            f32x4 c_[4];
#pragma unroll
            for (int qt = 0; qt < 4; ++qt) c_[qt] = (f32x4)0.f;
            const int key = w * 32 + mt * 16 + l15;
#pragma unroll
            for (int s = 0; s < 2; ++s) {
                bf16x8 ah = *(const bf16x8*)&U.k[0][key][s * 32 + quad * 8];
                bf16x8 al = *(const bf16x8*)&U.k[1][key][s * 32 + quad * 8];
#pragma unroll
                for (int qt = 0; qt < 4; ++qt) {
                    c_[qt] = __builtin_amdgcn_mfma_f32_16x16x32_bf16(
                        ah, qf[qt][s][0], c_[qt], 0, 0, 0);
                    c_[qt] = __builtin_amdgcn_mfma_f32_16x16x32_bf16(
                        ah, qf[qt][s][1], c_[qt], 0, 0, 0);
                    c_[qt] = __builtin_amdgcn_mfma_f32_16x16x32_bf16(
                        al, qf[qt][s][0], c_[qt], 0, 0, 0);
                }
            }
            // angular transform, pow8, write packed pairs to per-wave LDS
#pragma unroll
            for (int qt = 0; qt < 4; ++qt) {
                float w8[4];
#pragma unroll
                for (int r = 0; r < 4; ++r) {
                    float sim = fminf(fmaxf(c_[qt][r], -0.999f), 0.999f);
                    float sc  = 1.f - acosf(sim) * 0.31830988618379067f;
                    float ww  = fmaxf(sc, 1e-6f);
                    float w2 = ww * ww, w4 = w2 * w2;
                    w8[r] = w4 * w4;
                    partial[qt] += w8[r];
                }
                int2 pk;
                pk.x = packbf(w8[0], w8[1]);
                pk.y = packbf(w8[2], w8[3]);
                *(int2*)&Wls[w][16 * qt + l15][mt * 8 + 2 * quad] = pk;
            }
        }

        // PV: O[64q x 64d] partial over wave's 32 keys (1 kstep of 32)
#pragma unroll
        for (int qt = 0; qt < 4; ++qt) {
            union { int4 i4; bf16x8 v; } au;
            au.i4 = *(const int4*)&Wls[w][16 * qt + l15][quad * 4];
#pragma unroll
            for (int nd = 0; nd < 4; ++nd) {
                bf16x8 bv = *(const bf16x8*)&Vts[nd * 16 + l15][w * 32 + quad * 8];
                acc[qt][nd] = __builtin_amdgcn_mfma_f32_16x16x32_bf16(
                    au.v, bv, acc[qt][nd], 0, 0, 0);
            }
        }
    }

    // rowsum reduce: per q = 16*qt + l15
#pragma unroll
    for (int qt = 0; qt < 4; ++qt) {
        float p = partial[qt];
        p += __shfl_xor(p, 16);
        p += __shfl_xor(p, 32);
        if (quad == 0) Rbuf[w][qt * 16 + l15] = p;
    }
    __syncthreads();
    if (t < 64) {
        float s = Rbuf[0][t] + Rbuf[1][t] + Rbuf[2][t] + Rbuf[3][t];
        Rfin[t] = 1.f / (s + 1e-6f);
    }

    // cross-wave O reduction into U.obuf (rotating q-tile ownership)
    for (int rds = 0; rds < 4; ++rds) {
        __syncthreads();
        const int myqt = (w + rds) & 3;
#pragma unroll
        for (int nd = 0; nd < 4; ++nd)
#pragma unroll
            for (int r = 0; r < 4; ++r) {
                float* p = &U.obuf[myqt * 16 + quad * 4 + r][nd * 16 + l15];
                float v = acc[myqt][nd][r];
                if (rds == 0) *p = v; else *p += v;
            }
    }
    __syncthreads();

    // final write: row = t>>2, 16 cols per thread, scaled by 1/rowsum
    {
        const int row   = t >> 2;
        const int chunk = (t & 3) * 16;
        const float inv = Rfin[row];
        float* dst = Oa + (size_t)(b * TT + q0 + row) * DD + h * DK + chunk;
#pragma unroll
        for (int c = 0; c < 4; ++c) {
            float4 v = *(const float4*)&U.obuf[row][chunk + c * 4];
            v.x *= inv; v.y *= inv; v.z *= inv; v.w *= inv;
            *(float4*)(dst + c * 4) = v;
        }
    }
}

// ---------------------------------------------------------------------------
extern "C" void kernel_launch(void* const* d_in, const int* in_sizes, int n_in,
                              void* d_out, int out_size, void* d_ws, size_t ws_size,
                              hipStream_t stream)
{
    const float* x  = (const float*)d_in[0];
    const float* Wq = (const float*)d_in[1];
    const float* Wk = (const float*)d_in[2];
    const float* Wv = (const float*)d_in[3];
    const float* Wo = (const float*)d_in[4];
    const float* bo = (const float*)d_in[5];
    float* out = (float*)d_out;

    const int M = BB * TT;   // 4096
    const int N = DD;
    const int K = DD;

    const size_t MB = 1024 * 1024;
    char* ws = (char*)d_ws;
    float* Q0   = (float*)(ws);              // [0,16M)
    float* K0   = (float*)(ws + 16 * MB);    // [16M,32M)
    float* V0   = (float*)(ws + 32 * MB);    // [32M,48M)
    short* Qhi  = (short*)(ws + 48 * MB);    // [48M,56M)
    short* Qlo  = (short*)(ws + 56 * MB);    // [56M,64M)
    short* Khi  = (short*)(ws);              // reuse Q0 after q-normsplit
    short* Klo  = (short*)(ws + 8 * MB);
    short* Vt   = (short*)(ws + 16 * MB);    // reuse K0 after k-normsplit
    float* attn = (float*)(ws + 32 * MB);    // reuse V0 after vtrans

    dim3 gB(256);
    dim3 gGemm(N / 128, M / 64);

    gemm_mfma_nt<<<gGemm, gB, 0, stream>>>(x, Wq, nullptr, Q0, M, N, K, 0);
    gemm_mfma_nt<<<gGemm, gB, 0, stream>>>(x, Wk, nullptr, K0, M, N, K, 0);
    gemm_mfma_nt<<<gGemm, gB, 0, stream>>>(x, Wv, nullptr, V0, M, N, K, 0);

    const int nSeg = M * HH;  // 65536
    normsplit_kernel<<<nSeg / 4, gB, 0, stream>>>(Q0, Qhi, Qlo);
    normsplit_kernel<<<nSeg / 4, gB, 0, stream>>>(K0, Khi, Klo);
    vtrans_kernel<<<dim3(TT / 64, HH, BB), gB, 0, stream>>>(V0, Vt);

    attn_kernel<<<dim3(TT / 64, HH, BB), gB, 0, stream>>>(Qhi, Qlo, Khi, Klo, Vt, attn);

    gemm_mfma_nt<<<gGemm, gB, 0, stream>>>(attn, Wo, bo, out, M, N, K, 1);
}

// Round 5
// 751.457 us; speedup vs baseline: 1.0274x; 1.0274x over previous
//
#include <hip/hip_runtime.h>
#include <hip/hip_bf16.h>
#include <math.h>

// Problem constants
#define BB 2
#define TT 2048
#define DD 1024
#define HH 16
#define DK 64
#define KT 128            // keys per attention tile

typedef __attribute__((ext_vector_type(8))) short bf16x8;
typedef __attribute__((ext_vector_type(4))) float f32x4;

static __device__ __forceinline__ short f2bf(float f) {
    __hip_bfloat16 h = __float2bfloat16(f);
    union { __hip_bfloat16 h; short s; } u; u.h = h; return u.s;
}
static __device__ __forceinline__ float bf2f(short s) {
    union { short s; __hip_bfloat16 h; } u; u.s = s; return __bfloat162float(u.h);
}
static __device__ __forceinline__ int packbf(float a, float b) {
    unsigned int ua = (unsigned short)f2bf(a);
    unsigned int ub = (unsigned short)f2bf(b);
    return (int)(ua | (ub << 16));
}

// ---------------------------------------------------------------------------
// Split-bf16 MFMA GEMM: C[M,N] = A[M,K] @ Bw[N,K]^T (+bias). (unchanged R2)
// ---------------------------------------------------------------------------
__global__ __launch_bounds__(256) void gemm_mfma_nt(
    const float* __restrict__ A, const float* __restrict__ Bw,
    const float* __restrict__ bias, float* __restrict__ C,
    int M, int N, int K, int hasBias)
{
    __shared__ short Ah[64][40];
    __shared__ short Al[64][40];
    __shared__ short Bh[128][40];
    __shared__ short Bl[128][40];

    const int t    = threadIdx.x;
    const int m0   = blockIdx.y * 64;
    const int n0   = blockIdx.x * 128;
    const int lane = t & 63;
    const int w    = t >> 6;
    const int wm   = w >> 1;
    const int wn   = w & 1;
    const int l15  = lane & 15;
    const int quad = lane >> 4;

    const int ar = t >> 2, ac = (t & 3) * 8;
    const int br = t >> 1, bc = (t & 1) * 16;

    const float* Aptr = A + (size_t)(m0 + ar) * K + ac;
    const float* Bptr = Bw + (size_t)(n0 + br) * K + bc;

    f32x4 acc[2][4];
#pragma unroll
    for (int i = 0; i < 2; ++i)
#pragma unroll
        for (int j = 0; j < 4; ++j) acc[i][j] = (f32x4)0.f;

    for (int k0 = 0; k0 < K; k0 += 32) {
        float4 a0 = *(const float4*)(Aptr + k0);
        float4 a1 = *(const float4*)(Aptr + k0 + 4);
        float4 b0 = *(const float4*)(Bptr + k0);
        float4 b1 = *(const float4*)(Bptr + k0 + 4);
        float4 b2 = *(const float4*)(Bptr + k0 + 8);
        float4 b3 = *(const float4*)(Bptr + k0 + 12);

        __syncthreads();
        {
            union { short s[8]; int4 v; } ph, pl;
            float va[8] = {a0.x, a0.y, a0.z, a0.w, a1.x, a1.y, a1.z, a1.w};
#pragma unroll
            for (int j = 0; j < 8; ++j) {
                short h = f2bf(va[j]);
                ph.s[j] = h;
                pl.s[j] = f2bf(va[j] - bf2f(h));
            }
            *(int4*)&Ah[ar][ac] = ph.v;
            *(int4*)&Al[ar][ac] = pl.v;
        }
        {
            union { short s[8]; int4 v; } ph, pl;
            float vb[8] = {b0.x, b0.y, b0.z, b0.w, b1.x, b1.y, b1.z, b1.w};
#pragma unroll
            for (int j = 0; j < 8; ++j) {
                short h = f2bf(vb[j]);
                ph.s[j] = h;
                pl.s[j] = f2bf(vb[j] - bf2f(h));
            }
            *(int4*)&Bh[br][bc] = ph.v;
            *(int4*)&Bl[br][bc] = pl.v;
        }
        {
            union { short s[8]; int4 v; } ph, pl;
            float vb[8] = {b2.x, b2.y, b2.z, b2.w, b3.x, b3.y, b3.z, b3.w};
#pragma unroll
            for (int j = 0; j < 8; ++j) {
                short h = f2bf(vb[j]);
                ph.s[j] = h;
                pl.s[j] = f2bf(vb[j] - bf2f(h));
            }
            *(int4*)&Bh[br][bc + 8] = ph.v;
            *(int4*)&Bl[br][bc + 8] = pl.v;
        }
        __syncthreads();

        bf16x8 ah[2], al[2], bh[4], bl[4];
#pragma unroll
        for (int tm = 0; tm < 2; ++tm) {
            ah[tm] = *(const bf16x8*)&Ah[wm * 32 + tm * 16 + l15][quad * 8];
            al[tm] = *(const bf16x8*)&Al[wm * 32 + tm * 16 + l15][quad * 8];
        }
#pragma unroll
        for (int tn = 0; tn < 4; ++tn) {
            bh[tn] = *(const bf16x8*)&Bh[wn * 64 + tn * 16 + l15][quad * 8];
            bl[tn] = *(const bf16x8*)&Bl[wn * 64 + tn * 16 + l15][quad * 8];
        }
#pragma unroll
        for (int tm = 0; tm < 2; ++tm)
#pragma unroll
            for (int tn = 0; tn < 4; ++tn) {
                acc[tm][tn] = __builtin_amdgcn_mfma_f32_16x16x32_bf16(
                    ah[tm], bh[tn], acc[tm][tn], 0, 0, 0);
                acc[tm][tn] = __builtin_amdgcn_mfma_f32_16x16x32_bf16(
                    ah[tm], bl[tn], acc[tm][tn], 0, 0, 0);
                acc[tm][tn] = __builtin_amdgcn_mfma_f32_16x16x32_bf16(
                    al[tm], bh[tn], acc[tm][tn], 0, 0, 0);
            }
    }

#pragma unroll
    for (int tm = 0; tm < 2; ++tm)
#pragma unroll
        for (int tn = 0; tn < 4; ++tn) {
            const int col  = n0 + wn * 64 + tn * 16 + l15;
            const float bv = hasBias ? bias[col] : 0.f;
            const int rowb = m0 + wm * 32 + tm * 16 + quad * 4;
#pragma unroll
            for (int r = 0; r < 4; ++r)
                C[(size_t)(rowb + r) * N + col] = acc[tm][tn][r] + bv;
        }
}

// ---------------------------------------------------------------------------
// Normalize each 64-wide head segment; emit hi/lo split bf16 at [b][h][t][dk].
// ---------------------------------------------------------------------------
__global__ __launch_bounds__(256) void normsplit_kernel(
    const float* __restrict__ X, short* __restrict__ Hi, short* __restrict__ Lo)
{
    const int seg  = blockIdx.x * 4 + (threadIdx.x >> 6);
    const int lane = threadIdx.x & 63;
    const int row  = seg >> 4;   // b*T + t
    const int h    = seg & 15;
    float v = X[(size_t)row * DD + h * DK + lane];
    float s = v * v;
    s += __shfl_xor(s, 1);
    s += __shfl_xor(s, 2);
    s += __shfl_xor(s, 4);
    s += __shfl_xor(s, 8);
    s += __shfl_xor(s, 16);
    s += __shfl_xor(s, 32);
    float n = sqrtf(s);
    float vn = v / fmaxf(n, 1e-12f);
    const int b  = row >> 11;
    const int tt = row & 2047;
    size_t o = ((size_t)(b * HH + h) * TT + tt) * DK + lane;
    short hv = f2bf(vn);
    Hi[o] = hv;
    Lo[o] = f2bf(vn - bf2f(hv));
}

// ---------------------------------------------------------------------------
// V -> bf16 transposed [b][h][d][T].
// ---------------------------------------------------------------------------
__global__ __launch_bounds__(256) void vtrans_kernel(
    const float* __restrict__ V0, short* __restrict__ Vt)
{
    __shared__ short Vtmp[64][72];
    const int t  = threadIdx.x;
    const int t0 = blockIdx.x * 64;
    const int h  = blockIdx.y;
    const int b  = blockIdx.z;

    {
        const int i  = t >> 2;            // token row 0..63
        const int jc = (t & 3) * 16;      // dim chunk
        const float* src = V0 + (size_t)(b * TT + t0 + i) * DD + h * DK + jc;
#pragma unroll
        for (int c = 0; c < 4; ++c) {
            float4 v = *(const float4*)(src + c * 4);
            Vtmp[jc + c * 4 + 0][i] = f2bf(v.x);
            Vtmp[jc + c * 4 + 1][i] = f2bf(v.y);
            Vtmp[jc + c * 4 + 2][i] = f2bf(v.z);
            Vtmp[jc + c * 4 + 3][i] = f2bf(v.w);
        }
    }
    __syncthreads();
    {
        const int d  = t >> 2;
        const int kc = (t & 3) * 16;
        short* dst = Vt + ((size_t)((b * HH + h) * DK + d)) * TT + t0 + kc;
        *(int4*)(dst)     = *(const int4*)&Vtmp[d][kc];
        *(int4*)(dst + 8) = *(const int4*)&Vtmp[d][kc + 8];
    }
}

// ---------------------------------------------------------------------------
// MFMA angular attention. Grid (T/64, H, B), 256 threads (4 waves).
// Q-hi staged in LDS (read per tile); Q-lo hoisted (32 VGPRs).
// amdgpu_waves_per_eu(2,2): pin occupancy so LLVM's heuristic can't spill
// to chase >2 waves/EU (R3/R4: 1.9 GB scratch writes).
// LDS total 80128 B -> 2 blocks/CU.
// ---------------------------------------------------------------------------
__global__ __launch_bounds__(256)
__attribute__((amdgpu_waves_per_eu(2, 2)))
void attn_kernel(
    const short* __restrict__ Qhi, const short* __restrict__ Qlo,
    const short* __restrict__ Khi_g, const short* __restrict__ Klo_g,
    const short* __restrict__ Vt_g, float* __restrict__ Oa)
{
    __shared__ union {
        short k[2][128][68];          // [hi/lo][key][dk]  34816 B
        float obuf[64][68];           // epilogue O reduction
    } U;
    __shared__ short Vts[64][132];    // [d][key]          16896 B
    __shared__ int   Wls[4][64][18];  // [w][q][keypair]   18432 B
    __shared__ short Qls[64][68];     // [q][dk] hi         8704 B
    __shared__ float Rbuf[4][64];     //                    1024 B
    __shared__ float Rfin[64];        //                     256 B

    const int t    = threadIdx.x;
    const int lane = t & 63;
    const int w    = t >> 6;
    const int l15  = lane & 15;
    const int quad = lane >> 4;
    const int q0   = blockIdx.x * 64;
    const int h    = blockIdx.y;
    const int b    = blockIdx.z;
    const size_t bh = (size_t)(b * HH + h);

    // stage Q-hi into LDS (once)
    {
        const int row = t >> 2;
        const int col = (t & 3) * 16;
        const short* src = Qhi + (bh * TT + q0 + row) * DK + col;
        *(int4*)&Qls[row][col]     = *(const int4*)(src);
        *(int4*)&Qls[row][col + 8] = *(const int4*)(src + 8);
    }
    // hoist Q-lo B-frags (q = 16*t4 + l15, k = s*32 + quad*8): 32 VGPRs
    bf16x8 qlf[4][2];
    {
        const short* ql = Qlo + (bh * TT + q0) * DK;
#pragma unroll
        for (int t4 = 0; t4 < 4; ++t4)
#pragma unroll
            for (int s = 0; s < 2; ++s)
                qlf[t4][s] = *(const bf16x8*)(
                    ql + (size_t)(16 * t4 + l15) * DK + s * 32 + quad * 8);
    }

    f32x4 acc[4][4];   // [qt][nd] partial O
#pragma unroll
    for (int i = 0; i < 4; ++i)
#pragma unroll
        for (int j = 0; j < 4; ++j) acc[i][j] = (f32x4)0.f;
    float partial[4] = {0.f, 0.f, 0.f, 0.f};

    const short* kh_g = Khi_g + bh * TT * DK;
    const short* kl_g = Klo_g + bh * TT * DK;
    const short* vt_g = Vt_g + bh * (size_t)DK * TT;

    const int srow = t >> 1;          // K stage row 0..127
    const int scol = (t & 1) * 32;    // shorts
    const int vrow = t >> 2;          // V stage d 0..63
    const int vcol = (t & 3) * 32;    // shorts

    for (int k0 = 0; k0 < TT; k0 += KT) {
        int4 kh[4], kl[4], vv[4];
        {
            const short* kp = kh_g + (size_t)(k0 + srow) * DK + scol;
            const short* lp = kl_g + (size_t)(k0 + srow) * DK + scol;
            const short* vp = vt_g + (size_t)vrow * TT + k0 + vcol;
#pragma unroll
            for (int c = 0; c < 4; ++c) {
                kh[c] = *(const int4*)(kp + c * 8);
                kl[c] = *(const int4*)(lp + c * 8);
                vv[c] = *(const int4*)(vp + c * 8);
            }
        }
        __syncthreads();   // prev tile consumed (first iter: Qls staged)
#pragma unroll
        for (int c = 0; c < 4; ++c) {
            *(int4*)&U.k[0][srow][scol + c * 8] = kh[c];
            *(int4*)&U.k[1][srow][scol + c * 8] = kl[c];
            *(int4*)&Vts[vrow][vcol + c * 8]    = vv[c];
        }
        __syncthreads();

        // S^T tiles + transform; wave keys [w*32, w*32+32)
#pragma unroll
        for (int mt = 0; mt < 2; ++mt) {
            f32x4 c_[4];
#pragma unroll
            for (int qt = 0; qt < 4; ++qt) c_[qt] = (f32x4)0.f;
            const int key = w * 32 + mt * 16 + l15;
#pragma unroll
            for (int s = 0; s < 2; ++s) {
                bf16x8 ah = *(const bf16x8*)&U.k[0][key][s * 32 + quad * 8];
                bf16x8 al = *(const bf16x8*)&U.k[1][key][s * 32 + quad * 8];
#pragma unroll
                for (int qt = 0; qt < 4; ++qt) {
                    bf16x8 qh = *(const bf16x8*)&Qls[16 * qt + l15][s * 32 + quad * 8];
                    c_[qt] = __builtin_amdgcn_mfma_f32_16x16x32_bf16(
                        ah, qh, c_[qt], 0, 0, 0);
                    c_[qt] = __builtin_amdgcn_mfma_f32_16x16x32_bf16(
                        al, qh, c_[qt], 0, 0, 0);
                    c_[qt] = __builtin_amdgcn_mfma_f32_16x16x32_bf16(
                        ah, qlf[qt][s], c_[qt], 0, 0, 0);
                }
            }
            // angular transform, pow8, write packed pairs to per-wave LDS
#pragma unroll
            for (int qt = 0; qt < 4; ++qt) {
                float w8[4];
#pragma unroll
                for (int r = 0; r < 4; ++r) {
                    float sim = fminf(fmaxf(c_[qt][r], -0.999f), 0.999f);
                    float sc  = 1.f - acosf(sim) * 0.31830988618379067f;
                    float ww  = fmaxf(sc, 1e-6f);
                    float w2 = ww * ww, w4 = w2 * w2;
                    w8[r] = w4 * w4;
                    partial[qt] += w8[r];
                }
                int2 pk;
                pk.x = packbf(w8[0], w8[1]);
                pk.y = packbf(w8[2], w8[3]);
                *(int2*)&Wls[w][16 * qt + l15][mt * 8 + 2 * quad] = pk;
            }
        }

        // PV: O[64q x 64d] partial over wave's 32 keys (1 kstep of 32)
        bf16x8 bv[4];
#pragma unroll
        for (int nd = 0; nd < 4; ++nd)
            bv[nd] = *(const bf16x8*)&Vts[nd * 16 + l15][w * 32 + quad * 8];
#pragma unroll
        for (int qt = 0; qt < 4; ++qt) {
            bf16x8 av = *(const bf16x8*)&Wls[w][16 * qt + l15][quad * 4];
#pragma unroll
            for (int nd = 0; nd < 4; ++nd)
                acc[qt][nd] = __builtin_amdgcn_mfma_f32_16x16x32_bf16(
                    av, bv[nd], acc[qt][nd], 0, 0, 0);
        }
    }

    // rowsum reduce: per q = 16*qt + l15
#pragma unroll
    for (int qt = 0; qt < 4; ++qt) {
        float p = partial[qt];
        p += __shfl_xor(p, 16);
        p += __shfl_xor(p, 32);
        if (quad == 0) Rbuf[w][qt * 16 + l15] = p;
    }
    __syncthreads();
    if (t < 64) {
        float s = Rbuf[0][t] + Rbuf[1][t] + Rbuf[2][t] + Rbuf[3][t];
        Rfin[t] = 1.f / (s + 1e-6f);
    }

    // cross-wave O reduction into U.obuf (rotating q-tile ownership)
    for (int rds = 0; rds < 4; ++rds) {
        __syncthreads();
        const int myqt = (w + rds) & 3;
#pragma unroll
        for (int nd = 0; nd < 4; ++nd)
#pragma unroll
            for (int r = 0; r < 4; ++r) {
                float* p = &U.obuf[myqt * 16 + quad * 4 + r][nd * 16 + l15];
                float v = acc[myqt][nd][r];
                if (rds == 0) *p = v; else *p += v;
            }
    }
    __syncthreads();

    // final write: row = t>>2, 16 cols per thread, scaled by 1/rowsum
    {
        const int row   = t >> 2;
        const int chunk = (t & 3) * 16;
        const float inv = Rfin[row];
        float* dst = Oa + (size_t)(b * TT + q0 + row) * DD + h * DK + chunk;
#pragma unroll
        for (int c = 0; c < 4; ++c) {
            float4 v = *(const float4*)&U.obuf[row][chunk + c * 4];
            v.x *= inv; v.y *= inv; v.z *= inv; v.w *= inv;
            *(float4*)(dst + c * 4) = v;
        }
    }
}

// ---------------------------------------------------------------------------
extern "C" void kernel_launch(void* const* d_in, const int* in_sizes, int n_in,
                              void* d_out, int out_size, void* d_ws, size_t ws_size,
                              hipStream_t stream)
{
    const float* x  = (const float*)d_in[0];
    const float* Wq = (const float*)d_in[1];
    const float* Wk = (const float*)d_in[2];
    const float* Wv = (const float*)d_in[3];
    const float* Wo = (const float*)d_in[4];
    const float* bo = (const float*)d_in[5];
    float* out = (float*)d_out;

    const int M = BB * TT;   // 4096
    const int N = DD;
    const int K = DD;

    const size_t MB = 1024 * 1024;
    char* ws = (char*)d_ws;
    float* Q0   = (float*)(ws);              // [0,16M)
    float* K0   = (float*)(ws + 16 * MB);    // [16M,32M)
    float* V0   = (float*)(ws + 32 * MB);    // [32M,48M)
    short* Qhi  = (short*)(ws + 48 * MB);    // [48M,56M)
    short* Qlo  = (short*)(ws + 56 * MB);    // [56M,64M)
    short* Khi  = (short*)(ws);              // reuse Q0 after q-normsplit
    short* Klo  = (short*)(ws + 8 * MB);
    short* Vt   = (short*)(ws + 16 * MB);    // reuse K0 after k-normsplit
    float* attn = (float*)(ws + 32 * MB);    // reuse V0 after vtrans

    dim3 gB(256);
    dim3 gGemm(N / 128, M / 64);

    gemm_mfma_nt<<<gGemm, gB, 0, stream>>>(x, Wq, nullptr, Q0, M, N, K, 0);
    gemm_mfma_nt<<<gGemm, gB, 0, stream>>>(x, Wk, nullptr, K0, M, N, K, 0);
    gemm_mfma_nt<<<gGemm, gB, 0, stream>>>(x, Wv, nullptr, V0, M, N, K, 0);

    const int nSeg = M * HH;  // 65536
    normsplit_kernel<<<nSeg / 4, gB, 0, stream>>>(Q0, Qhi, Qlo);
    normsplit_kernel<<<nSeg / 4, gB, 0, stream>>>(K0, Khi, Klo);
    vtrans_kernel<<<dim3(TT / 64, HH, BB), gB, 0, stream>>>(V0, Vt);

    attn_kernel<<<dim3(TT / 64, HH, BB), gB, 0, stream>>>(Qhi, Qlo, Khi, Klo, Vt, attn);

    gemm_mfma_nt<<<gGemm, gB, 0, stream>>>(attn, Wo, bo, out, M, N, K, 1);
}

// Round 6
// 509.872 us; speedup vs baseline: 1.5142x; 1.4738x over previous
//
#include <hip/hip_runtime.h>
#include <hip/hip_bf16.h>
#include <math.h>

// Problem constants
#define BB 2
#define TT 2048
#define DD 1024
#define HH 16
#define DK 64
#define KT 128            // keys per attention tile

typedef __attribute__((ext_vector_type(8))) short bf16x8;
typedef __attribute__((ext_vector_type(4))) float f32x4;

static __device__ __forceinline__ short f2bf(float f) {
    __hip_bfloat16 h = __float2bfloat16(f);
    union { __hip_bfloat16 h; short s; } u; u.h = h; return u.s;
}
static __device__ __forceinline__ float bf2f(short s) {
    union { short s; __hip_bfloat16 h; } u; u.s = s; return __bfloat162float(u.h);
}
static __device__ __forceinline__ int packbf(float a, float b) {
    unsigned int ua = (unsigned short)f2bf(a);
    unsigned int ub = (unsigned short)f2bf(b);
    return (int)(ua | (ub << 16));
}

// ---------------------------------------------------------------------------
// Split-bf16 MFMA GEMM: C[M,N] = A[M,K] @ Bw[N,K]^T (+bias). (unchanged R2)
// ---------------------------------------------------------------------------
__global__ __launch_bounds__(256) void gemm_mfma_nt(
    const float* __restrict__ A, const float* __restrict__ Bw,
    const float* __restrict__ bias, float* __restrict__ C,
    int M, int N, int K, int hasBias)
{
    __shared__ short Ah[64][40];
    __shared__ short Al[64][40];
    __shared__ short Bh[128][40];
    __shared__ short Bl[128][40];

    const int t    = threadIdx.x;
    const int m0   = blockIdx.y * 64;
    const int n0   = blockIdx.x * 128;
    const int lane = t & 63;
    const int w    = t >> 6;
    const int wm   = w >> 1;
    const int wn   = w & 1;
    const int l15  = lane & 15;
    const int quad = lane >> 4;

    const int ar = t >> 2, ac = (t & 3) * 8;
    const int br = t >> 1, bc = (t & 1) * 16;

    const float* Aptr = A + (size_t)(m0 + ar) * K + ac;
    const float* Bptr = Bw + (size_t)(n0 + br) * K + bc;

    f32x4 acc[2][4];
#pragma unroll
    for (int i = 0; i < 2; ++i)
#pragma unroll
        for (int j = 0; j < 4; ++j) acc[i][j] = (f32x4)0.f;

    for (int k0 = 0; k0 < K; k0 += 32) {
        float4 a0 = *(const float4*)(Aptr + k0);
        float4 a1 = *(const float4*)(Aptr + k0 + 4);
        float4 b0 = *(const float4*)(Bptr + k0);
        float4 b1 = *(const float4*)(Bptr + k0 + 4);
        float4 b2 = *(const float4*)(Bptr + k0 + 8);
        float4 b3 = *(const float4*)(Bptr + k0 + 12);

        __syncthreads();
        {
            union { short s[8]; int4 v; } ph, pl;
            float va[8] = {a0.x, a0.y, a0.z, a0.w, a1.x, a1.y, a1.z, a1.w};
#pragma unroll
            for (int j = 0; j < 8; ++j) {
                short h = f2bf(va[j]);
                ph.s[j] = h;
                pl.s[j] = f2bf(va[j] - bf2f(h));
            }
            *(int4*)&Ah[ar][ac] = ph.v;
            *(int4*)&Al[ar][ac] = pl.v;
        }
        {
            union { short s[8]; int4 v; } ph, pl;
            float vb[8] = {b0.x, b0.y, b0.z, b0.w, b1.x, b1.y, b1.z, b1.w};
#pragma unroll
            for (int j = 0; j < 8; ++j) {
                short h = f2bf(vb[j]);
                ph.s[j] = h;
                pl.s[j] = f2bf(vb[j] - bf2f(h));
            }
            *(int4*)&Bh[br][bc] = ph.v;
            *(int4*)&Bl[br][bc] = pl.v;
        }
        {
            union { short s[8]; int4 v; } ph, pl;
            float vb[8] = {b2.x, b2.y, b2.z, b2.w, b3.x, b3.y, b3.z, b3.w};
#pragma unroll
            for (int j = 0; j < 8; ++j) {
                short h = f2bf(vb[j]);
                ph.s[j] = h;
                pl.s[j] = f2bf(vb[j] - bf2f(h));
            }
            *(int4*)&Bh[br][bc + 8] = ph.v;
            *(int4*)&Bl[br][bc + 8] = pl.v;
        }
        __syncthreads();

        bf16x8 ah[2], al[2], bh[4], bl[4];
#pragma unroll
        for (int tm = 0; tm < 2; ++tm) {
            ah[tm] = *(const bf16x8*)&Ah[wm * 32 + tm * 16 + l15][quad * 8];
            al[tm] = *(const bf16x8*)&Al[wm * 32 + tm * 16 + l15][quad * 8];
        }
#pragma unroll
        for (int tn = 0; tn < 4; ++tn) {
            bh[tn] = *(const bf16x8*)&Bh[wn * 64 + tn * 16 + l15][quad * 8];
            bl[tn] = *(const bf16x8*)&Bl[wn * 64 + tn * 16 + l15][quad * 8];
        }
#pragma unroll
        for (int tm = 0; tm < 2; ++tm)
#pragma unroll
            for (int tn = 0; tn < 4; ++tn) {
                acc[tm][tn] = __builtin_amdgcn_mfma_f32_16x16x32_bf16(
                    ah[tm], bh[tn], acc[tm][tn], 0, 0, 0);
                acc[tm][tn] = __builtin_amdgcn_mfma_f32_16x16x32_bf16(
                    ah[tm], bl[tn], acc[tm][tn], 0, 0, 0);
                acc[tm][tn] = __builtin_amdgcn_mfma_f32_16x16x32_bf16(
                    al[tm], bh[tn], acc[tm][tn], 0, 0, 0);
            }
    }

#pragma unroll
    for (int tm = 0; tm < 2; ++tm)
#pragma unroll
        for (int tn = 0; tn < 4; ++tn) {
            const int col  = n0 + wn * 64 + tn * 16 + l15;
            const float bv = hasBias ? bias[col] : 0.f;
            const int rowb = m0 + wm * 32 + tm * 16 + quad * 4;
#pragma unroll
            for (int r = 0; r < 4; ++r)
                C[(size_t)(rowb + r) * N + col] = acc[tm][tn][r] + bv;
        }
}

// ---------------------------------------------------------------------------
// Normalize each 64-wide head segment; emit hi/lo split bf16 at [b][h][t][dk].
// ---------------------------------------------------------------------------
__global__ __launch_bounds__(256) void normsplit_kernel(
    const float* __restrict__ X, short* __restrict__ Hi, short* __restrict__ Lo)
{
    const int seg  = blockIdx.x * 4 + (threadIdx.x >> 6);
    const int lane = threadIdx.x & 63;
    const int row  = seg >> 4;   // b*T + t
    const int h    = seg & 15;
    float v = X[(size_t)row * DD + h * DK + lane];
    float s = v * v;
    s += __shfl_xor(s, 1);
    s += __shfl_xor(s, 2);
    s += __shfl_xor(s, 4);
    s += __shfl_xor(s, 8);
    s += __shfl_xor(s, 16);
    s += __shfl_xor(s, 32);
    float n = sqrtf(s);
    float vn = v / fmaxf(n, 1e-12f);
    const int b  = row >> 11;
    const int tt = row & 2047;
    size_t o = ((size_t)(b * HH + h) * TT + tt) * DK + lane;
    short hv = f2bf(vn);
    Hi[o] = hv;
    Lo[o] = f2bf(vn - bf2f(hv));
}

// ---------------------------------------------------------------------------
// V -> bf16 transposed [b][h][d][T].
// ---------------------------------------------------------------------------
__global__ __launch_bounds__(256) void vtrans_kernel(
    const float* __restrict__ V0, short* __restrict__ Vt)
{
    __shared__ short Vtmp[64][72];
    const int t  = threadIdx.x;
    const int t0 = blockIdx.x * 64;
    const int h  = blockIdx.y;
    const int b  = blockIdx.z;

    {
        const int i  = t >> 2;            // token row 0..63
        const int jc = (t & 3) * 16;      // dim chunk
        const float* src = V0 + (size_t)(b * TT + t0 + i) * DD + h * DK + jc;
#pragma unroll
        for (int c = 0; c < 4; ++c) {
            float4 v = *(const float4*)(src + c * 4);
            Vtmp[jc + c * 4 + 0][i] = f2bf(v.x);
            Vtmp[jc + c * 4 + 1][i] = f2bf(v.y);
            Vtmp[jc + c * 4 + 2][i] = f2bf(v.z);
            Vtmp[jc + c * 4 + 3][i] = f2bf(v.w);
        }
    }
    __syncthreads();
    {
        const int d  = t >> 2;
        const int kc = (t & 3) * 16;
        short* dst = Vt + ((size_t)((b * HH + h) * DK + d)) * TT + t0 + kc;
        *(int4*)(dst)     = *(const int4*)&Vtmp[d][kc];
        *(int4*)(dst + 8) = *(const int4*)&Vtmp[d][kc + 8];
    }
}

// ---------------------------------------------------------------------------
// MFMA angular attention, low-register restructure.
// Grid (T/64, H, B), 256 threads (4 waves), 64 queries/block, 128-key tiles.
// Phase A (per tile): wave w computes S^T for its 32 keys x all 64 q
//   (K-hi from LDS, K-lo straight from global regs, Q hi/lo from LDS),
//   transforms, writes bf16 W into shared Ws[64q][128k].
// Phase B: wave w computes O[16q x 64d] for q-tile w over ALL 128 keys
//   -> acc is only 4 f32x4 (16 regs), no cross-wave O reduction.
// Peak live regs ~110 < 128 -> no scratch spills (R3-R5: 1.9 GB spill traffic).
// LDS 70,400 B -> 2 blocks/CU.
// ---------------------------------------------------------------------------
__global__ __launch_bounds__(256) void attn_kernel(
    const short* __restrict__ Qhi, const short* __restrict__ Qlo,
    const short* __restrict__ Khi_g, const short* __restrict__ Klo_g,
    const short* __restrict__ Vt_g, float* __restrict__ Oa)
{
    __shared__ short Khs[128][68];   // K-hi [key][dk]   17408 B
    __shared__ short Vts[64][132];   // V    [d][key]    16896 B
    __shared__ short Ws[64][136];    // W    [q][key]    17408 B
    __shared__ short Qhs[64][68];    // Q-hi [q][dk]      8704 B
    __shared__ short Qls[64][68];    // Q-lo [q][dk]      8704 B
    __shared__ float Rbuf[4][64];    //                   1024 B
    __shared__ float Rfin[64];       //                    256 B

    const int t    = threadIdx.x;
    const int lane = t & 63;
    const int w    = t >> 6;
    const int l15  = lane & 15;
    const int quad = lane >> 4;
    const int q0   = blockIdx.x * 64;
    const int h    = blockIdx.y;
    const int b    = blockIdx.z;
    const size_t bh = (size_t)(b * HH + h);

    // stage Q hi/lo into LDS (once)
    {
        const int row = t >> 2;
        const int col = (t & 3) * 16;
        const short* sh = Qhi + (bh * TT + q0 + row) * DK + col;
        const short* sl = Qlo + (bh * TT + q0 + row) * DK + col;
        *(int4*)&Qhs[row][col]     = *(const int4*)(sh);
        *(int4*)&Qhs[row][col + 8] = *(const int4*)(sh + 8);
        *(int4*)&Qls[row][col]     = *(const int4*)(sl);
        *(int4*)&Qls[row][col + 8] = *(const int4*)(sl + 8);
    }

    f32x4 acc[4];    // O[16q x 64d] for q-tile w: [nd]
#pragma unroll
    for (int j = 0; j < 4; ++j) acc[j] = (f32x4)0.f;
    float partial[4] = {0.f, 0.f, 0.f, 0.f};

    const short* kh_g = Khi_g + bh * TT * DK;
    const short* kl_g = Klo_g + bh * TT * DK;
    const short* vt_g = Vt_g + bh * (size_t)DK * TT;

    const int srow = t >> 1;          // K stage row 0..127
    const int scol = (t & 1) * 32;    // shorts
    const int vrow = t >> 2;          // V stage d 0..63
    const int vcol = (t & 3) * 32;    // shorts

    for (int k0 = 0; k0 < TT; k0 += KT) {
        // global loads for this tile: K-hi + V staging, K-lo frags direct
        int4 kh[4], vv[4];
        bf16x8 klo[2][2];             // [mt][s]
        {
            const short* kp = kh_g + (size_t)(k0 + srow) * DK + scol;
            const short* vp = vt_g + (size_t)vrow * TT + k0 + vcol;
#pragma unroll
            for (int c = 0; c < 4; ++c) {
                kh[c] = *(const int4*)(kp + c * 8);
                vv[c] = *(const int4*)(vp + c * 8);
            }
#pragma unroll
            for (int mt = 0; mt < 2; ++mt)
#pragma unroll
                for (int s = 0; s < 2; ++s)
                    klo[mt][s] = *(const bf16x8*)(
                        kl_g + (size_t)(k0 + w * 32 + mt * 16 + l15) * DK +
                        s * 32 + quad * 8);
        }
        __syncthreads();   // prev tile's PV done (Vts/Ws free); Q staged (1st)
#pragma unroll
        for (int c = 0; c < 4; ++c) {
            *(int4*)&Khs[srow][scol + c * 8] = kh[c];
            *(int4*)&Vts[vrow][vcol + c * 8] = vv[c];
        }
        __syncthreads();

        // Phase A: S^T for wave's 32 keys x 64 q, transform, write Ws
#pragma unroll
        for (int qt = 0; qt < 4; ++qt) {
            f32x4 c_[2];
            c_[0] = (f32x4)0.f;
            c_[1] = (f32x4)0.f;
#pragma unroll
            for (int s = 0; s < 2; ++s) {
                bf16x8 qh = *(const bf16x8*)&Qhs[qt * 16 + l15][s * 32 + quad * 8];
                bf16x8 ql = *(const bf16x8*)&Qls[qt * 16 + l15][s * 32 + quad * 8];
#pragma unroll
                for (int mt = 0; mt < 2; ++mt) {
                    bf16x8 ah = *(const bf16x8*)&Khs[w * 32 + mt * 16 + l15][s * 32 + quad * 8];
                    c_[mt] = __builtin_amdgcn_mfma_f32_16x16x32_bf16(
                        ah, qh, c_[mt], 0, 0, 0);
                    c_[mt] = __builtin_amdgcn_mfma_f32_16x16x32_bf16(
                        ah, ql, c_[mt], 0, 0, 0);
                    c_[mt] = __builtin_amdgcn_mfma_f32_16x16x32_bf16(
                        klo[mt][s], qh, c_[mt], 0, 0, 0);
                }
            }
#pragma unroll
            for (int mt = 0; mt < 2; ++mt) {
                float w8[4];
#pragma unroll
                for (int r = 0; r < 4; ++r) {
                    float sim = fminf(fmaxf(c_[mt][r], -0.999f), 0.999f);
                    float sc  = 1.f - acosf(sim) * 0.31830988618379067f;
                    float ww  = fmaxf(sc, 1e-6f);
                    float w2 = ww * ww, w4 = w2 * w2;
                    w8[r] = w4 * w4;
                    partial[qt] += w8[r];
                }
                int2 pk;
                pk.x = packbf(w8[0], w8[1]);
                pk.y = packbf(w8[2], w8[3]);
                // W[q = qt*16+l15][key = w*32 + mt*16 + quad*4 + r]
                *(int2*)&Ws[qt * 16 + l15][w * 32 + mt * 16 + quad * 4] = pk;
            }
        }
        __syncthreads();   // Ws complete across waves

        // Phase B: PV for q-tile w over all 128 keys
#pragma unroll
        for (int kstep = 0; kstep < 4; ++kstep) {
            bf16x8 av = *(const bf16x8*)&Ws[16 * w + l15][kstep * 32 + quad * 8];
#pragma unroll
            for (int nd = 0; nd < 4; ++nd) {
                bf16x8 bv = *(const bf16x8*)&Vts[nd * 16 + l15][kstep * 32 + quad * 8];
                acc[nd] = __builtin_amdgcn_mfma_f32_16x16x32_bf16(
                    av, bv, acc[nd], 0, 0, 0);
            }
        }
    }

    // rowsum: partial[qt] covers q = qt*16+l15 over wave's keys
#pragma unroll
    for (int qt = 0; qt < 4; ++qt) {
        float p = partial[qt];
        p += __shfl_xor(p, 16);
        p += __shfl_xor(p, 32);
        if (quad == 0) Rbuf[w][qt * 16 + l15] = p;
    }
    __syncthreads();
    if (t < 64) {
        float s = Rbuf[0][t] + Rbuf[1][t] + Rbuf[2][t] + Rbuf[3][t];
        Rfin[t] = 1.f / (s + 1e-6f);
    }
    __syncthreads();

    // store: acc[nd][r] = O[q = 16w + quad*4 + r][d = nd*16 + l15]
#pragma unroll
    for (int r = 0; r < 4; ++r) {
        const int q = 16 * w + quad * 4 + r;
        const float inv = Rfin[q];
        float* dst = Oa + (size_t)(b * TT + q0 + q) * DD + h * DK + l15;
#pragma unroll
        for (int nd = 0; nd < 4; ++nd)
            dst[nd * 16] = acc[nd][r] * inv;
    }
}

// ---------------------------------------------------------------------------
extern "C" void kernel_launch(void* const* d_in, const int* in_sizes, int n_in,
                              void* d_out, int out_size, void* d_ws, size_t ws_size,
                              hipStream_t stream)
{
    const float* x  = (const float*)d_in[0];
    const float* Wq = (const float*)d_in[1];
    const float* Wk = (const float*)d_in[2];
    const float* Wv = (const float*)d_in[3];
    const float* Wo = (const float*)d_in[4];
    const float* bo = (const float*)d_in[5];
    float* out = (float*)d_out;

    const int M = BB * TT;   // 4096
    const int N = DD;
    const int K = DD;

    const size_t MB = 1024 * 1024;
    char* ws = (char*)d_ws;
    float* Q0   = (float*)(ws);              // [0,16M)
    float* K0   = (float*)(ws + 16 * MB);    // [16M,32M)
    float* V0   = (float*)(ws + 32 * MB);    // [32M,48M)
    short* Qhi  = (short*)(ws + 48 * MB);    // [48M,56M)
    short* Qlo  = (short*)(ws + 56 * MB);    // [56M,64M)
    short* Khi  = (short*)(ws);              // reuse Q0 after q-normsplit
    short* Klo  = (short*)(ws + 8 * MB);
    short* Vt   = (short*)(ws + 16 * MB);    // reuse K0 after k-normsplit
    float* attn = (float*)(ws + 32 * MB);    // reuse V0 after vtrans

    dim3 gB(256);
    dim3 gGemm(N / 128, M / 64);

    gemm_mfma_nt<<<gGemm, gB, 0, stream>>>(x, Wq, nullptr, Q0, M, N, K, 0);
    gemm_mfma_nt<<<gGemm, gB, 0, stream>>>(x, Wk, nullptr, K0, M, N, K, 0);
    gemm_mfma_nt<<<gGemm, gB, 0, stream>>>(x, Wv, nullptr, V0, M, N, K, 0);

    const int nSeg = M * HH;  // 65536
    normsplit_kernel<<<nSeg / 4, gB, 0, stream>>>(Q0, Qhi, Qlo);
    normsplit_kernel<<<nSeg / 4, gB, 0, stream>>>(K0, Khi, Klo);
    vtrans_kernel<<<dim3(TT / 64, HH, BB), gB, 0, stream>>>(V0, Vt);

    attn_kernel<<<dim3(TT / 64, HH, BB), gB, 0, stream>>>(Qhi, Qlo, Khi, Klo, Vt, attn);

    gemm_mfma_nt<<<gGemm, gB, 0, stream>>>(attn, Wo, bo, out, M, N, K, 1);
}

// Round 7
// 482.608 us; speedup vs baseline: 1.5997x; 1.0565x over previous
//
#include <hip/hip_runtime.h>
#include <hip/hip_bf16.h>
#include <math.h>

// Problem constants
#define BB 2
#define TT 2048
#define DD 1024
#define HH 16
#define DK 64
#define KT 128            // keys per attention tile

typedef __attribute__((ext_vector_type(8))) short bf16x8;
typedef __attribute__((ext_vector_type(4))) float f32x4;

static __device__ __forceinline__ short f2bf(float f) {
    __hip_bfloat16 h = __float2bfloat16(f);
    union { __hip_bfloat16 h; short s; } u; u.h = h; return u.s;
}
static __device__ __forceinline__ float bf2f(short s) {
    union { short s; __hip_bfloat16 h; } u; u.s = s; return __bfloat162float(u.h);
}
static __device__ __forceinline__ int packbf(float a, float b) {
    unsigned int ua = (unsigned short)f2bf(a);
    unsigned int ub = (unsigned short)f2bf(b);
    return (int)(ua | (ub << 16));
}
// async 16B global->LDS (lane i writes ldsbase + i*16)
static __device__ __forceinline__ void g2lds16(const void* g, void* l) {
    __builtin_amdgcn_global_load_lds(
        (const __attribute__((address_space(1))) unsigned int*)g,
        (__attribute__((address_space(3))) unsigned int*)l, 16, 0, 0);
}
// acos via A&S 4.4.46 (|err| <= ~1e-7 rad), input in [-0.999, 0.999]
static __device__ __forceinline__ float acos_poly(float x) {
    float ax = fabsf(x);
    float p = fmaf(ax, -0.0012624911f, 0.0066700901f);
    p = fmaf(ax, p, -0.0170881256f);
    p = fmaf(ax, p, 0.0308918810f);
    p = fmaf(ax, p, -0.0501743046f);
    p = fmaf(ax, p, 0.0889789874f);
    p = fmaf(ax, p, -0.2145988016f);
    p = fmaf(ax, p, 1.5707963050f);
    float a = sqrtf(1.f - ax) * p;
    return x >= 0.f ? a : 3.14159265358979f - a;
}

// ---------------------------------------------------------------------------
// Split-bf16 MFMA GEMM: C[M,N] = A[M,K] @ Bw[N,K]^T (+bias). (unchanged R2)
// ---------------------------------------------------------------------------
__global__ __launch_bounds__(256) void gemm_mfma_nt(
    const float* __restrict__ A, const float* __restrict__ Bw,
    const float* __restrict__ bias, float* __restrict__ C,
    int M, int N, int K, int hasBias)
{
    __shared__ short Ah[64][40];
    __shared__ short Al[64][40];
    __shared__ short Bh[128][40];
    __shared__ short Bl[128][40];

    const int t    = threadIdx.x;
    const int m0   = blockIdx.y * 64;
    const int n0   = blockIdx.x * 128;
    const int lane = t & 63;
    const int w    = t >> 6;
    const int wm   = w >> 1;
    const int wn   = w & 1;
    const int l15  = lane & 15;
    const int quad = lane >> 4;

    const int ar = t >> 2, ac = (t & 3) * 8;
    const int br = t >> 1, bc = (t & 1) * 16;

    const float* Aptr = A + (size_t)(m0 + ar) * K + ac;
    const float* Bptr = Bw + (size_t)(n0 + br) * K + bc;

    f32x4 acc[2][4];
#pragma unroll
    for (int i = 0; i < 2; ++i)
#pragma unroll
        for (int j = 0; j < 4; ++j) acc[i][j] = (f32x4)0.f;

    for (int k0 = 0; k0 < K; k0 += 32) {
        float4 a0 = *(const float4*)(Aptr + k0);
        float4 a1 = *(const float4*)(Aptr + k0 + 4);
        float4 b0 = *(const float4*)(Bptr + k0);
        float4 b1 = *(const float4*)(Bptr + k0 + 4);
        float4 b2 = *(const float4*)(Bptr + k0 + 8);
        float4 b3 = *(const float4*)(Bptr + k0 + 12);

        __syncthreads();
        {
            union { short s[8]; int4 v; } ph, pl;
            float va[8] = {a0.x, a0.y, a0.z, a0.w, a1.x, a1.y, a1.z, a1.w};
#pragma unroll
            for (int j = 0; j < 8; ++j) {
                short h = f2bf(va[j]);
                ph.s[j] = h;
                pl.s[j] = f2bf(va[j] - bf2f(h));
            }
            *(int4*)&Ah[ar][ac] = ph.v;
            *(int4*)&Al[ar][ac] = pl.v;
        }
        {
            union { short s[8]; int4 v; } ph, pl;
            float vb[8] = {b0.x, b0.y, b0.z, b0.w, b1.x, b1.y, b1.z, b1.w};
#pragma unroll
            for (int j = 0; j < 8; ++j) {
                short h = f2bf(vb[j]);
                ph.s[j] = h;
                pl.s[j] = f2bf(vb[j] - bf2f(h));
            }
            *(int4*)&Bh[br][bc] = ph.v;
            *(int4*)&Bl[br][bc] = pl.v;
        }
        {
            union { short s[8]; int4 v; } ph, pl;
            float vb[8] = {b2.x, b2.y, b2.z, b2.w, b3.x, b3.y, b3.z, b3.w};
#pragma unroll
            for (int j = 0; j < 8; ++j) {
                short h = f2bf(vb[j]);
                ph.s[j] = h;
                pl.s[j] = f2bf(vb[j] - bf2f(h));
            }
            *(int4*)&Bh[br][bc + 8] = ph.v;
            *(int4*)&Bl[br][bc + 8] = pl.v;
        }
        __syncthreads();

        bf16x8 ah[2], al[2], bh[4], bl[4];
#pragma unroll
        for (int tm = 0; tm < 2; ++tm) {
            ah[tm] = *(const bf16x8*)&Ah[wm * 32 + tm * 16 + l15][quad * 8];
            al[tm] = *(const bf16x8*)&Al[wm * 32 + tm * 16 + l15][quad * 8];
        }
#pragma unroll
        for (int tn = 0; tn < 4; ++tn) {
            bh[tn] = *(const bf16x8*)&Bh[wn * 64 + tn * 16 + l15][quad * 8];
            bl[tn] = *(const bf16x8*)&Bl[wn * 64 + tn * 16 + l15][quad * 8];
        }
#pragma unroll
        for (int tm = 0; tm < 2; ++tm)
#pragma unroll
            for (int tn = 0; tn < 4; ++tn) {
                acc[tm][tn] = __builtin_amdgcn_mfma_f32_16x16x32_bf16(
                    ah[tm], bh[tn], acc[tm][tn], 0, 0, 0);
                acc[tm][tn] = __builtin_amdgcn_mfma_f32_16x16x32_bf16(
                    ah[tm], bl[tn], acc[tm][tn], 0, 0, 0);
                acc[tm][tn] = __builtin_amdgcn_mfma_f32_16x16x32_bf16(
                    al[tm], bh[tn], acc[tm][tn], 0, 0, 0);
            }
    }

#pragma unroll
    for (int tm = 0; tm < 2; ++tm)
#pragma unroll
        for (int tn = 0; tn < 4; ++tn) {
            const int col  = n0 + wn * 64 + tn * 16 + l15;
            const float bv = hasBias ? bias[col] : 0.f;
            const int rowb = m0 + wm * 32 + tm * 16 + quad * 4;
#pragma unroll
            for (int r = 0; r < 4; ++r)
                C[(size_t)(rowb + r) * N + col] = acc[tm][tn][r] + bv;
        }
}

// ---------------------------------------------------------------------------
// Normalize each 64-wide head segment; emit hi/lo split bf16 at [b][h][t][dk].
// ---------------------------------------------------------------------------
__global__ __launch_bounds__(256) void normsplit_kernel(
    const float* __restrict__ X, short* __restrict__ Hi, short* __restrict__ Lo)
{
    const int seg  = blockIdx.x * 4 + (threadIdx.x >> 6);
    const int lane = threadIdx.x & 63;
    const int row  = seg >> 4;   // b*T + t
    const int h    = seg & 15;
    float v = X[(size_t)row * DD + h * DK + lane];
    float s = v * v;
    s += __shfl_xor(s, 1);
    s += __shfl_xor(s, 2);
    s += __shfl_xor(s, 4);
    s += __shfl_xor(s, 8);
    s += __shfl_xor(s, 16);
    s += __shfl_xor(s, 32);
    float n = sqrtf(s);
    float vn = v / fmaxf(n, 1e-12f);
    const int b  = row >> 11;
    const int tt = row & 2047;
    size_t o = ((size_t)(b * HH + h) * TT + tt) * DK + lane;
    short hv = f2bf(vn);
    Hi[o] = hv;
    Lo[o] = f2bf(vn - bf2f(hv));
}

// ---------------------------------------------------------------------------
// V -> bf16 transposed [b][h][d][T].
// ---------------------------------------------------------------------------
__global__ __launch_bounds__(256) void vtrans_kernel(
    const float* __restrict__ V0, short* __restrict__ Vt)
{
    __shared__ short Vtmp[64][72];
    const int t  = threadIdx.x;
    const int t0 = blockIdx.x * 64;
    const int h  = blockIdx.y;
    const int b  = blockIdx.z;

    {
        const int i  = t >> 2;            // token row 0..63
        const int jc = (t & 3) * 16;      // dim chunk
        const float* src = V0 + (size_t)(b * TT + t0 + i) * DD + h * DK + jc;
#pragma unroll
        for (int c = 0; c < 4; ++c) {
            float4 v = *(const float4*)(src + c * 4);
            Vtmp[jc + c * 4 + 0][i] = f2bf(v.x);
            Vtmp[jc + c * 4 + 1][i] = f2bf(v.y);
            Vtmp[jc + c * 4 + 2][i] = f2bf(v.z);
            Vtmp[jc + c * 4 + 3][i] = f2bf(v.w);
        }
    }
    __syncthreads();
    {
        const int d  = t >> 2;
        const int kc = (t & 3) * 16;
        short* dst = Vt + ((size_t)((b * HH + h) * DK + d)) * TT + t0 + kc;
        *(int4*)(dst)     = *(const int4*)&Vtmp[d][kc];
        *(int4*)(dst + 8) = *(const int4*)&Vtmp[d][kc + 8];
    }
}

// ---------------------------------------------------------------------------
// MFMA angular attention v3: global_load_lds staging (zero staging VGPRs).
// Grid (T/64, H, B), 256 threads (4 waves), 64 queries/block, 128-key tiles.
// LDS chunk-major layouts so DMA lane->slot mapping is contiguous AND frag
// ds_read_b128 is bank-uniform:
//   Khs[ccdk=dk/8][key][8]  (K-hi)    16384 B
//   Vts[kc=key/8][d][8]               16384 B
// Phase A: wave w -> S^T for its 32 keys x 64 q (K-lo frags from global
// regs), poly-acos transform, bf16 W -> shared Ws. Phase B: wave w -> full
// O[16q x 64d] over 128 keys (acc = 16 regs). No spills expected.
// LDS 69,888 B -> 2 blocks/CU.
// ---------------------------------------------------------------------------
__global__ __launch_bounds__(256) void attn_kernel(
    const short* __restrict__ Qhi, const short* __restrict__ Qlo,
    const short* __restrict__ Khi_g, const short* __restrict__ Klo_g,
    const short* __restrict__ Vt_g, float* __restrict__ Oa)
{
    __shared__ short Khs[8][128][8];  // [dk-chunk][key][8]   16384 B
    __shared__ short Vts[16][64][8];  // [key-chunk][d][8]    16384 B
    __shared__ short Ws[64][136];     // [q][key]             17408 B
    __shared__ short Qhs[64][72];     // [q][dk]               9216 B
    __shared__ short Qls[64][72];     // [q][dk]               9216 B
    __shared__ float Rbuf[4][64];     //                       1024 B
    __shared__ float Rfin[64];        //                        256 B

    const int t    = threadIdx.x;
    const int lane = t & 63;
    const int w    = t >> 6;
    const int l15  = lane & 15;
    const int quad = lane >> 4;
    const int q0   = blockIdx.x * 64;
    const int h    = blockIdx.y;
    const int b    = blockIdx.z;
    const size_t bh = (size_t)(b * HH + h);

    // stage Q hi/lo into LDS (once)
    {
        const int row = t >> 2;
        const int col = (t & 3) * 16;
        const short* sh = Qhi + (bh * TT + q0 + row) * DK + col;
        const short* sl = Qlo + (bh * TT + q0 + row) * DK + col;
        *(int4*)&Qhs[row][col]     = *(const int4*)(sh);
        *(int4*)&Qhs[row][col + 8] = *(const int4*)(sh + 8);
        *(int4*)&Qls[row][col]     = *(const int4*)(sl);
        *(int4*)&Qls[row][col + 8] = *(const int4*)(sl + 8);
    }

    f32x4 acc[4];    // O[16q x 64d] for q-tile w
#pragma unroll
    for (int j = 0; j < 4; ++j) acc[j] = (f32x4)0.f;
    float partial[4] = {0.f, 0.f, 0.f, 0.f};

    const short* kh_g = Khi_g + bh * TT * DK;
    const short* kl_g = Klo_g + bh * TT * DK;
    const short* vt_g = Vt_g + bh * (size_t)DK * TT;

    // K-lo frags for tile 0 (prefetched before first barrier)
    bf16x8 klo[2][2];
#pragma unroll
    for (int mt = 0; mt < 2; ++mt)
#pragma unroll
        for (int s = 0; s < 2; ++s)
            klo[mt][s] = *(const bf16x8*)(
                kl_g + (size_t)(w * 32 + mt * 16 + l15) * DK + s * 32 + quad * 8);

    for (int k0 = 0; k0 < TT; k0 += KT) {
        __syncthreads();   // prev tile fully consumed (1st iter: Q staged)

        // async staging: K-hi 16 KB + V 16 KB, wave-partitioned
#pragma unroll
        for (int i = 0; i < 2; ++i) {
            const int cc = w * 2 + i;
#pragma unroll
            for (int half = 0; half < 2; ++half)
                g2lds16(kh_g + (size_t)(k0 + half * 64 + lane) * DK + cc * 8,
                        &Khs[cc][half * 64][0]);
        }
#pragma unroll
        for (int j = 0; j < 4; ++j) {
            const int kc = w * 4 + j;
            g2lds16(vt_g + (size_t)lane * TT + k0 + kc * 8,
                    &Vts[kc][0][0]);
        }
        __syncthreads();   // vmcnt drained -> Khs/Vts valid

        // Phase A: S^T for wave's 32 keys x 64 q, transform, write Ws
#pragma unroll
        for (int qt = 0; qt < 4; ++qt) {
            f32x4 c_[2];
            c_[0] = (f32x4)0.f;
            c_[1] = (f32x4)0.f;
#pragma unroll
            for (int s = 0; s < 2; ++s) {
                bf16x8 qh = *(const bf16x8*)&Qhs[qt * 16 + l15][s * 32 + quad * 8];
                bf16x8 ql = *(const bf16x8*)&Qls[qt * 16 + l15][s * 32 + quad * 8];
#pragma unroll
                for (int mt = 0; mt < 2; ++mt) {
                    bf16x8 ah = *(const bf16x8*)&Khs[s * 4 + quad][w * 32 + mt * 16 + l15][0];
                    c_[mt] = __builtin_amdgcn_mfma_f32_16x16x32_bf16(
                        ah, qh, c_[mt], 0, 0, 0);
                    c_[mt] = __builtin_amdgcn_mfma_f32_16x16x32_bf16(
                        ah, ql, c_[mt], 0, 0, 0);
                    c_[mt] = __builtin_amdgcn_mfma_f32_16x16x32_bf16(
                        klo[mt][s], qh, c_[mt], 0, 0, 0);
                }
            }
#pragma unroll
            for (int mt = 0; mt < 2; ++mt) {
                float w8[4];
#pragma unroll
                for (int r = 0; r < 4; ++r) {
                    float sim = fminf(fmaxf(c_[mt][r], -0.999f), 0.999f);
                    float sc  = fmaf(-acos_poly(sim), 0.31830988618379067f, 1.f);
                    float ww  = fmaxf(sc, 1e-6f);
                    float w2 = ww * ww, w4 = w2 * w2;
                    w8[r] = w4 * w4;
                    partial[qt] += w8[r];
                }
                int2 pk;
                pk.x = packbf(w8[0], w8[1]);
                pk.y = packbf(w8[2], w8[3]);
                *(int2*)&Ws[qt * 16 + l15][w * 32 + mt * 16 + quad * 4] = pk;
            }
        }

        // prefetch next tile's K-lo frags (overlaps Phase B)
        if (k0 + KT < TT) {
#pragma unroll
            for (int mt = 0; mt < 2; ++mt)
#pragma unroll
                for (int s = 0; s < 2; ++s)
                    klo[mt][s] = *(const bf16x8*)(
                        kl_g + (size_t)(k0 + KT + w * 32 + mt * 16 + l15) * DK +
                        s * 32 + quad * 8);
        }
        __syncthreads();   // Ws complete across waves

        // Phase B: PV for q-tile w over all 128 keys
#pragma unroll
        for (int kstep = 0; kstep < 4; ++kstep) {
            bf16x8 av = *(const bf16x8*)&Ws[16 * w + l15][kstep * 32 + quad * 8];
#pragma unroll
            for (int nd = 0; nd < 4; ++nd) {
                bf16x8 bv = *(const bf16x8*)&Vts[kstep * 4 + quad][nd * 16 + l15][0];
                acc[nd] = __builtin_amdgcn_mfma_f32_16x16x32_bf16(
                    av, bv, acc[nd], 0, 0, 0);
            }
        }
    }

    // rowsum: partial[qt] covers q = qt*16+l15 over wave's keys
#pragma unroll
    for (int qt = 0; qt < 4; ++qt) {
        float p = partial[qt];
        p += __shfl_xor(p, 16);
        p += __shfl_xor(p, 32);
        if (quad == 0) Rbuf[w][qt * 16 + l15] = p;
    }
    __syncthreads();
    if (t < 64) {
        float s = Rbuf[0][t] + Rbuf[1][t] + Rbuf[2][t] + Rbuf[3][t];
        Rfin[t] = 1.f / (s + 1e-6f);
    }
    __syncthreads();

    // store: acc[nd][r] = O[q = 16w + quad*4 + r][d = nd*16 + l15]
#pragma unroll
    for (int r = 0; r < 4; ++r) {
        const int q = 16 * w + quad * 4 + r;
        const float inv = Rfin[q];
        float* dst = Oa + (size_t)(b * TT + q0 + q) * DD + h * DK + l15;
#pragma unroll
        for (int nd = 0; nd < 4; ++nd)
            dst[nd * 16] = acc[nd][r] * inv;
    }
}

// ---------------------------------------------------------------------------
extern "C" void kernel_launch(void* const* d_in, const int* in_sizes, int n_in,
                              void* d_out, int out_size, void* d_ws, size_t ws_size,
                              hipStream_t stream)
{
    const float* x  = (const float*)d_in[0];
    const float* Wq = (const float*)d_in[1];
    const float* Wk = (const float*)d_in[2];
    const float* Wv = (const float*)d_in[3];
    const float* Wo = (const float*)d_in[4];
    const float* bo = (const float*)d_in[5];
    float* out = (float*)d_out;

    const int M = BB * TT;   // 4096
    const int N = DD;
    const int K = DD;

    const size_t MB = 1024 * 1024;
    char* ws = (char*)d_ws;
    float* Q0   = (float*)(ws);              // [0,16M)
    float* K0   = (float*)(ws + 16 * MB);    // [16M,32M)
    float* V0   = (float*)(ws + 32 * MB);    // [32M,48M)
    short* Qhi  = (short*)(ws + 48 * MB);    // [48M,56M)
    short* Qlo  = (short*)(ws + 56 * MB);    // [56M,64M)
    short* Khi  = (short*)(ws);              // reuse Q0 after q-normsplit
    short* Klo  = (short*)(ws + 8 * MB);
    short* Vt   = (short*)(ws + 16 * MB);    // reuse K0 after k-normsplit
    float* attn = (float*)(ws + 32 * MB);    // reuse V0 after vtrans

    dim3 gB(256);
    dim3 gGemm(N / 128, M / 64);

    gemm_mfma_nt<<<gGemm, gB, 0, stream>>>(x, Wq, nullptr, Q0, M, N, K, 0);
    gemm_mfma_nt<<<gGemm, gB, 0, stream>>>(x, Wk, nullptr, K0, M, N, K, 0);
    gemm_mfma_nt<<<gGemm, gB, 0, stream>>>(x, Wv, nullptr, V0, M, N, K, 0);

    const int nSeg = M * HH;  // 65536
    normsplit_kernel<<<nSeg / 4, gB, 0, stream>>>(Q0, Qhi, Qlo);
    normsplit_kernel<<<nSeg / 4, gB, 0, stream>>>(K0, Khi, Klo);
    vtrans_kernel<<<dim3(TT / 64, HH, BB), gB, 0, stream>>>(V0, Vt);

    attn_kernel<<<dim3(TT / 64, HH, BB), gB, 0, stream>>>(Qhi, Qlo, Khi, Klo, Vt, attn);

    gemm_mfma_nt<<<gGemm, gB, 0, stream>>>(attn, Wo, bo, out, M, N, K, 1);
}

// Round 8
// 438.963 us; speedup vs baseline: 1.7588x; 1.0994x over previous
//
#include <hip/hip_runtime.h>
#include <hip/hip_bf16.h>
#include <math.h>

// Problem constants
#define BB 2
#define TT 2048
#define DD 1024
#define HH 16
#define DK 64
#define KT 128            // keys per attention tile

typedef __attribute__((ext_vector_type(8))) short bf16x8;
typedef __attribute__((ext_vector_type(4))) float f32x4;
typedef __attribute__((ext_vector_type(2))) float f32x2;

static __device__ __forceinline__ short f2bf(float f) {
    __hip_bfloat16 h = __float2bfloat16(f);
    union { __hip_bfloat16 h; short s; } u; u.h = h; return u.s;
}
static __device__ __forceinline__ float bf2f(short s) {
    union { short s; __hip_bfloat16 h; } u; u.s = s; return __bfloat162float(u.h);
}
// async 16B global->LDS (lane i writes ldsbase + i*16)
static __device__ __forceinline__ void g2lds16(const void* g, void* l) {
    __builtin_amdgcn_global_load_lds(
        (const __attribute__((address_space(1))) unsigned int*)g,
        (__attribute__((address_space(3))) unsigned int*)l, 16, 0, 0);
}

// w = (1 - acos(clip(s,±0.999))/pi)^8 for a pair; rs accumulates pair sums.
// acos/pi via A&S 4.4.45 deg-3 (|err|<=5e-5 rad -> dt<=1.6e-5); the
// reference's max(score,1e-6) is dead: clamp guarantees t >= 0.01424.
// float2 ops lower to v_pk_{fma,mul,add}_f32 on gfx950.
static __device__ __forceinline__ f32x2 w8pair(f32x2 s, f32x2& rs) {
    f32x2 x;
    x.x = fminf(fmaxf(s.x, -0.999f), 0.999f);
    x.y = fminf(fmaxf(s.y, -0.999f), 0.999f);
    f32x2 ax;
    ax.x = fabsf(x.x);
    ax.y = fabsf(x.y);
    f32x2 p = ax * -0.0059617f + 0.0236380f;
    p = p * ax + (-0.0675180f);
    p = p * ax + 0.49997851f;
    f32x2 u;
    u.x = sqrtf(1.f - ax.x);
    u.y = sqrtf(1.f - ax.y);
    f32x2 uq = u * p;
    f32x2 t;
    t.x = (x.x >= 0.f) ? (1.f - uq.x) : uq.x;
    t.y = (x.y >= 0.f) ? (1.f - uq.y) : uq.y;
    f32x2 t2 = t * t;
    f32x2 t4 = t2 * t2;
    f32x2 t8 = t4 * t4;
    rs += t8;
    return t8;
}
// round-half-up bf16 pair pack (values are positive normals <= 1)
static __device__ __forceinline__ int packbf2(f32x2 v) {
    union { float f; unsigned u; } a, b;
    a.f = v.x; b.f = v.y;
    unsigned lo = (a.u + 0x8000u) >> 16;
    unsigned hi = (b.u + 0x8000u) & 0xFFFF0000u;
    return (int)(lo | hi);
}

// ---------------------------------------------------------------------------
// Split-bf16 MFMA GEMM: C[M,N] = A[M,K] @ Bw[N,K]^T (+bias).
// NPROD=3: Ah*Bh + Ah*Bl + Al*Bh (full split, used for final Wo GEMM).
// NPROD=2: Ah*Bh + Al*Bh (weights RNE-bf16; used for Q/K/V projections,
//          err sigma ~1e-3 on unit-variance outputs — inside budget).
// ---------------------------------------------------------------------------
template<int NPROD>
__global__ __launch_bounds__(256) void gemm_mfma_nt(
    const float* __restrict__ A, const float* __restrict__ Bw,
    const float* __restrict__ bias, float* __restrict__ C,
    int M, int N, int K, int hasBias)
{
    __shared__ short Ah[64][40];
    __shared__ short Al[64][40];
    __shared__ short Bh[128][40];
    __shared__ short Bl[128][40];   // eliminated by LDS-DCE when NPROD==2

    const int t    = threadIdx.x;
    const int m0   = blockIdx.y * 64;
    const int n0   = blockIdx.x * 128;
    const int lane = t & 63;
    const int w    = t >> 6;
    const int wm   = w >> 1;
    const int wn   = w & 1;
    const int l15  = lane & 15;
    const int quad = lane >> 4;

    const int ar = t >> 2, ac = (t & 3) * 8;
    const int br = t >> 1, bc = (t & 1) * 16;

    const float* Aptr = A + (size_t)(m0 + ar) * K + ac;
    const float* Bptr = Bw + (size_t)(n0 + br) * K + bc;

    f32x4 acc[2][4];
#pragma unroll
    for (int i = 0; i < 2; ++i)
#pragma unroll
        for (int j = 0; j < 4; ++j) acc[i][j] = (f32x4)0.f;

    for (int k0 = 0; k0 < K; k0 += 32) {
        float4 a0 = *(const float4*)(Aptr + k0);
        float4 a1 = *(const float4*)(Aptr + k0 + 4);
        float4 b0 = *(const float4*)(Bptr + k0);
        float4 b1 = *(const float4*)(Bptr + k0 + 4);
        float4 b2 = *(const float4*)(Bptr + k0 + 8);
        float4 b3 = *(const float4*)(Bptr + k0 + 12);

        __syncthreads();
        {
            union { short s[8]; int4 v; } ph, pl;
            float va[8] = {a0.x, a0.y, a0.z, a0.w, a1.x, a1.y, a1.z, a1.w};
#pragma unroll
            for (int j = 0; j < 8; ++j) {
                short h = f2bf(va[j]);
                ph.s[j] = h;
                pl.s[j] = f2bf(va[j] - bf2f(h));
            }
            *(int4*)&Ah[ar][ac] = ph.v;
            *(int4*)&Al[ar][ac] = pl.v;
        }
        {
            union { short s[8]; int4 v; } ph, pl;
            float vb[8] = {b0.x, b0.y, b0.z, b0.w, b1.x, b1.y, b1.z, b1.w};
#pragma unroll
            for (int j = 0; j < 8; ++j) {
                short h = f2bf(vb[j]);
                ph.s[j] = h;
                if (NPROD == 3) pl.s[j] = f2bf(vb[j] - bf2f(h));
            }
            *(int4*)&Bh[br][bc] = ph.v;
            if (NPROD == 3) *(int4*)&Bl[br][bc] = pl.v;
        }
        {
            union { short s[8]; int4 v; } ph, pl;
            float vb[8] = {b2.x, b2.y, b2.z, b2.w, b3.x, b3.y, b3.z, b3.w};
#pragma unroll
            for (int j = 0; j < 8; ++j) {
                short h = f2bf(vb[j]);
                ph.s[j] = h;
                if (NPROD == 3) pl.s[j] = f2bf(vb[j] - bf2f(h));
            }
            *(int4*)&Bh[br][bc + 8] = ph.v;
            if (NPROD == 3) *(int4*)&Bl[br][bc + 8] = pl.v;
        }
        __syncthreads();

        bf16x8 ah[2], al[2], bh[4];
#pragma unroll
        for (int tm = 0; tm < 2; ++tm) {
            ah[tm] = *(const bf16x8*)&Ah[wm * 32 + tm * 16 + l15][quad * 8];
            al[tm] = *(const bf16x8*)&Al[wm * 32 + tm * 16 + l15][quad * 8];
        }
#pragma unroll
        for (int tn = 0; tn < 4; ++tn)
            bh[tn] = *(const bf16x8*)&Bh[wn * 64 + tn * 16 + l15][quad * 8];
#pragma unroll
        for (int tm = 0; tm < 2; ++tm)
#pragma unroll
            for (int tn = 0; tn < 4; ++tn) {
                acc[tm][tn] = __builtin_amdgcn_mfma_f32_16x16x32_bf16(
                    ah[tm], bh[tn], acc[tm][tn], 0, 0, 0);
                acc[tm][tn] = __builtin_amdgcn_mfma_f32_16x16x32_bf16(
                    al[tm], bh[tn], acc[tm][tn], 0, 0, 0);
                if (NPROD == 3) {
                    bf16x8 bl = *(const bf16x8*)&Bl[wn * 64 + tn * 16 + l15][quad * 8];
                    acc[tm][tn] = __builtin_amdgcn_mfma_f32_16x16x32_bf16(
                        ah[tm], bl, acc[tm][tn], 0, 0, 0);
                }
            }
    }

#pragma unroll
    for (int tm = 0; tm < 2; ++tm)
#pragma unroll
        for (int tn = 0; tn < 4; ++tn) {
            const int col  = n0 + wn * 64 + tn * 16 + l15;
            const float bv = hasBias ? bias[col] : 0.f;
            const int rowb = m0 + wm * 32 + tm * 16 + quad * 4;
#pragma unroll
            for (int r = 0; r < 4; ++r)
                C[(size_t)(rowb + r) * N + col] = acc[tm][tn][r] + bv;
        }
}

// ---------------------------------------------------------------------------
// Normalize each 64-wide head segment; emit hi (and optionally lo) split
// bf16 at [b][h][t][dk]. Lo==nullptr skips the low half (used for K).
// ---------------------------------------------------------------------------
__global__ __launch_bounds__(256) void normsplit_kernel(
    const float* __restrict__ X, short* __restrict__ Hi, short* __restrict__ Lo)
{
    const int seg  = blockIdx.x * 4 + (threadIdx.x >> 6);
    const int lane = threadIdx.x & 63;
    const int row  = seg >> 4;   // b*T + t
    const int h    = seg & 15;
    float v = X[(size_t)row * DD + h * DK + lane];
    float s = v * v;
    s += __shfl_xor(s, 1);
    s += __shfl_xor(s, 2);
    s += __shfl_xor(s, 4);
    s += __shfl_xor(s, 8);
    s += __shfl_xor(s, 16);
    s += __shfl_xor(s, 32);
    float n = sqrtf(s);
    float vn = v / fmaxf(n, 1e-12f);
    const int b  = row >> 11;
    const int tt = row & 2047;
    size_t o = ((size_t)(b * HH + h) * TT + tt) * DK + lane;
    short hv = f2bf(vn);
    Hi[o] = hv;
    if (Lo) Lo[o] = f2bf(vn - bf2f(hv));
}

// ---------------------------------------------------------------------------
// V -> bf16 transposed [b][h][d][T].
// ---------------------------------------------------------------------------
__global__ __launch_bounds__(256) void vtrans_kernel(
    const float* __restrict__ V0, short* __restrict__ Vt)
{
    __shared__ short Vtmp[64][72];
    const int t  = threadIdx.x;
    const int t0 = blockIdx.x * 64;
    const int h  = blockIdx.y;
    const int b  = blockIdx.z;

    {
        const int i  = t >> 2;            // token row 0..63
        const int jc = (t & 3) * 16;      // dim chunk
        const float* src = V0 + (size_t)(b * TT + t0 + i) * DD + h * DK + jc;
#pragma unroll
        for (int c = 0; c < 4; ++c) {
            float4 v = *(const float4*)(src + c * 4);
            Vtmp[jc + c * 4 + 0][i] = f2bf(v.x);
            Vtmp[jc + c * 4 + 1][i] = f2bf(v.y);
            Vtmp[jc + c * 4 + 2][i] = f2bf(v.z);
            Vtmp[jc + c * 4 + 3][i] = f2bf(v.w);
        }
    }
    __syncthreads();
    {
        const int d  = t >> 2;
        const int kc = (t & 3) * 16;
        short* dst = Vt + ((size_t)((b * HH + h) * DK + d)) * TT + t0 + kc;
        *(int4*)(dst)     = *(const int4*)&Vtmp[d][kc];
        *(int4*)(dst + 8) = *(const int4*)&Vtmp[d][kc + 8];
    }
}

// ---------------------------------------------------------------------------
// MFMA angular attention v4. Grid (T/64, H, B), 256 threads (4 waves).
// Same structure as R7 (global_load_lds staging, Phase A S^T per wave-keys,
// Phase B full-O per wave-qtile) minus the K-lo product (2 MFMA per
// (qt,s,mt) — sim err ~1.4e-4), with packed-f32 deg-3 transform.
// ---------------------------------------------------------------------------
__global__ __launch_bounds__(256) void attn_kernel(
    const short* __restrict__ Qhi, const short* __restrict__ Qlo,
    const short* __restrict__ Khi_g, const short* __restrict__ Vt_g,
    float* __restrict__ Oa)
{
    __shared__ short Khs[8][128][8];  // [dk-chunk][key][8]   16384 B
    __shared__ short Vts[16][64][8];  // [key-chunk][d][8]    16384 B
    __shared__ short Ws[64][136];     // [q][key]             17408 B
    __shared__ short Qhs[64][72];     // [q][dk]               9216 B
    __shared__ short Qls[64][72];     // [q][dk]               9216 B
    __shared__ float Rbuf[4][64];     //                       1024 B
    __shared__ float Rfin[64];        //                        256 B

    const int t    = threadIdx.x;
    const int lane = t & 63;
    const int w    = t >> 6;
    const int l15  = lane & 15;
    const int quad = lane >> 4;
    const int q0   = blockIdx.x * 64;
    const int h    = blockIdx.y;
    const int b    = blockIdx.z;
    const size_t bh = (size_t)(b * HH + h);

    // stage Q hi/lo into LDS (once)
    {
        const int row = t >> 2;
        const int col = (t & 3) * 16;
        const short* sh = Qhi + (bh * TT + q0 + row) * DK + col;
        const short* sl = Qlo + (bh * TT + q0 + row) * DK + col;
        *(int4*)&Qhs[row][col]     = *(const int4*)(sh);
        *(int4*)&Qhs[row][col + 8] = *(const int4*)(sh + 8);
        *(int4*)&Qls[row][col]     = *(const int4*)(sl);
        *(int4*)&Qls[row][col + 8] = *(const int4*)(sl + 8);
    }

    f32x4 acc[4];    // O[16q x 64d] for q-tile w
#pragma unroll
    for (int j = 0; j < 4; ++j) acc[j] = (f32x4)0.f;
    f32x2 rs2[4];
#pragma unroll
    for (int j = 0; j < 4; ++j) rs2[j] = (f32x2)0.f;

    const short* kh_g = Khi_g + bh * TT * DK;
    const short* vt_g = Vt_g + bh * (size_t)DK * TT;

    for (int k0 = 0; k0 < TT; k0 += KT) {
        __syncthreads();   // prev tile fully consumed (1st iter: Q staged)

        // async staging: K-hi 16 KB + V 16 KB, wave-partitioned
#pragma unroll
        for (int i = 0; i < 2; ++i) {
            const int cc = w * 2 + i;
#pragma unroll
            for (int half = 0; half < 2; ++half)
                g2lds16(kh_g + (size_t)(k0 + half * 64 + lane) * DK + cc * 8,
                        &Khs[cc][half * 64][0]);
        }
#pragma unroll
        for (int j = 0; j < 4; ++j) {
            const int kc = w * 4 + j;
            g2lds16(vt_g + (size_t)lane * TT + k0 + kc * 8,
                    &Vts[kc][0][0]);
        }
        __syncthreads();   // vmcnt drained -> Khs/Vts valid

        // Phase A: S^T for wave's 32 keys x 64 q, transform, write Ws
#pragma unroll
        for (int qt = 0; qt < 4; ++qt) {
            f32x4 c_[2];
            c_[0] = (f32x4)0.f;
            c_[1] = (f32x4)0.f;
#pragma unroll
            for (int s = 0; s < 2; ++s) {
                bf16x8 qh = *(const bf16x8*)&Qhs[qt * 16 + l15][s * 32 + quad * 8];
                bf16x8 ql = *(const bf16x8*)&Qls[qt * 16 + l15][s * 32 + quad * 8];
#pragma unroll
                for (int mt = 0; mt < 2; ++mt) {
                    bf16x8 ah = *(const bf16x8*)&Khs[s * 4 + quad][w * 32 + mt * 16 + l15][0];
                    c_[mt] = __builtin_amdgcn_mfma_f32_16x16x32_bf16(
                        ah, qh, c_[mt], 0, 0, 0);
                    c_[mt] = __builtin_amdgcn_mfma_f32_16x16x32_bf16(
                        ah, ql, c_[mt], 0, 0, 0);
                }
            }
#pragma unroll
            for (int mt = 0; mt < 2; ++mt) {
                f32x2 p01, p23;
                p01.x = c_[mt][0]; p01.y = c_[mt][1];
                p23.x = c_[mt][2]; p23.y = c_[mt][3];
                f32x2 w01 = w8pair(p01, rs2[qt]);
                f32x2 w23 = w8pair(p23, rs2[qt]);
                int2 pk;
                pk.x = packbf2(w01);
                pk.y = packbf2(w23);
                *(int2*)&Ws[qt * 16 + l15][w * 32 + mt * 16 + quad * 4] = pk;
            }
        }
        __syncthreads();   // Ws complete across waves

        // Phase B: PV for q-tile w over all 128 keys
#pragma unroll
        for (int kstep = 0; kstep < 4; ++kstep) {
            bf16x8 av = *(const bf16x8*)&Ws[16 * w + l15][kstep * 32 + quad * 8];
#pragma unroll
            for (int nd = 0; nd < 4; ++nd) {
                bf16x8 bv = *(const bf16x8*)&Vts[kstep * 4 + quad][nd * 16 + l15][0];
                acc[nd] = __builtin_amdgcn_mfma_f32_16x16x32_bf16(
                    av, bv, acc[nd], 0, 0, 0);
            }
        }
    }

    // rowsum: rs2[qt] covers q = qt*16+l15 over wave's keys
#pragma unroll
    for (int qt = 0; qt < 4; ++qt) {
        float p = rs2[qt].x + rs2[qt].y;
        p += __shfl_xor(p, 16);
        p += __shfl_xor(p, 32);
        if (quad == 0) Rbuf[w][qt * 16 + l15] = p;
    }
    __syncthreads();
    if (t < 64) {
        float s = Rbuf[0][t] + Rbuf[1][t] + Rbuf[2][t] + Rbuf[3][t];
        Rfin[t] = 1.f / (s + 1e-6f);
    }
    __syncthreads();

    // store: acc[nd][r] = O[q = 16w + quad*4 + r][d = nd*16 + l15]
#pragma unroll
    for (int r = 0; r < 4; ++r) {
        const int q = 16 * w + quad * 4 + r;
        const float inv = Rfin[q];
        float* dst = Oa + (size_t)(b * TT + q0 + q) * DD + h * DK + l15;
#pragma unroll
        for (int nd = 0; nd < 4; ++nd)
            dst[nd * 16] = acc[nd][r] * inv;
    }
}

// ---------------------------------------------------------------------------
extern "C" void kernel_launch(void* const* d_in, const int* in_sizes, int n_in,
                              void* d_out, int out_size, void* d_ws, size_t ws_size,
                              hipStream_t stream)
{
    const float* x  = (const float*)d_in[0];
    const float* Wq = (const float*)d_in[1];
    const float* Wk = (const float*)d_in[2];
    const float* Wv = (const float*)d_in[3];
    const float* Wo = (const float*)d_in[4];
    const float* bo = (const float*)d_in[5];
    float* out = (float*)d_out;

    const int M = BB * TT;   // 4096
    const int N = DD;
    const int K = DD;

    const size_t MB = 1024 * 1024;
    char* ws = (char*)d_ws;
    float* Q0   = (float*)(ws);              // [0,16M)
    float* K0   = (float*)(ws + 16 * MB);    // [16M,32M)
    float* V0   = (float*)(ws + 32 * MB);    // [32M,48M)
    short* Qhi  = (short*)(ws + 48 * MB);    // [48M,56M)
    short* Qlo  = (short*)(ws + 56 * MB);    // [56M,64M)
    short* Khi  = (short*)(ws);              // reuse Q0 after q-normsplit
    short* Vt   = (short*)(ws + 16 * MB);    // reuse K0 after k-normsplit
    float* attn = (float*)(ws + 32 * MB);    // reuse V0 after vtrans

    dim3 gB(256);
    dim3 gGemm(N / 128, M / 64);

    gemm_mfma_nt<2><<<gGemm, gB, 0, stream>>>(x, Wq, nullptr, Q0, M, N, K, 0);
    gemm_mfma_nt<2><<<gGemm, gB, 0, stream>>>(x, Wk, nullptr, K0, M, N, K, 0);
    gemm_mfma_nt<2><<<gGemm, gB, 0, stream>>>(x, Wv, nullptr, V0, M, N, K, 0);

    const int nSeg = M * HH;  // 65536
    normsplit_kernel<<<nSeg / 4, gB, 0, stream>>>(Q0, Qhi, Qlo);
    normsplit_kernel<<<nSeg / 4, gB, 0, stream>>>(K0, Khi, nullptr);
    vtrans_kernel<<<dim3(TT / 64, HH, BB), gB, 0, stream>>>(V0, Vt);

    attn_kernel<<<dim3(TT / 64, HH, BB), gB, 0, stream>>>(Qhi, Qlo, Khi, Vt, attn);

    gemm_mfma_nt<3><<<gGemm, gB, 0, stream>>>(attn, Wo, bo, out, M, N, K, 1);
}

// Round 10
// 403.692 us; speedup vs baseline: 1.9124x; 1.0874x over previous
//
#include <hip/hip_runtime.h>
#include <hip/hip_bf16.h>
#include <hip/hip_fp16.h>
#include <math.h>

// Problem constants
#define BB 2
#define TT 2048
#define DD 1024
#define HH 16
#define DK 64
#define KT 128            // keys per attention tile

typedef _Float16 f16x8 __attribute__((ext_vector_type(8)));
typedef __fp16 fp16x2 __attribute__((ext_vector_type(2)));
typedef __attribute__((ext_vector_type(4))) float f32x4;
typedef __attribute__((ext_vector_type(2))) float f32x2;

// async 16B global->LDS (lane i writes ldsbase + i*16)
static __device__ __forceinline__ void g2lds16(const void* g, void* l) {
    __builtin_amdgcn_global_load_lds(
        (const __attribute__((address_space(1))) unsigned int*)g,
        (__attribute__((address_space(3))) unsigned int*)l, 16, 0, 0);
}

// w = (1 - acos(clip(s,±0.999))/pi)^8 for a pair; rs accumulates pair sums.
// acos/pi via A&S 4.4.45 deg-3 (|err|<=5e-5 rad); reference's max(.,1e-6)
// is dead (clamp => t >= 0.0142). float2 ops lower to v_pk_* on gfx950.
static __device__ __forceinline__ f32x2 w8pair(f32x2 s, f32x2& rs) {
    f32x2 x;
    x.x = fminf(fmaxf(s.x, -0.999f), 0.999f);
    x.y = fminf(fmaxf(s.y, -0.999f), 0.999f);
    f32x2 ax;
    ax.x = fabsf(x.x);
    ax.y = fabsf(x.y);
    f32x2 p = ax * -0.0059617f + 0.0236380f;
    p = p * ax + (-0.0675180f);
    p = p * ax + 0.49997851f;
    f32x2 u;
    u.x = sqrtf(1.f - ax.x);
    u.y = sqrtf(1.f - ax.y);
    f32x2 uq = u * p;
    f32x2 t;
    t.x = (x.x >= 0.f) ? (1.f - uq.x) : uq.x;
    t.y = (x.y >= 0.f) ? (1.f - uq.y) : uq.y;
    f32x2 t2 = t * t;
    f32x2 t4 = t2 * t2;
    f32x2 t8 = t4 * t4;
    rs += t8;
    return t8;
}
// one-instruction f16 pair pack (RTZ; |err|<=2^-11 rel, fine for W)
static __device__ __forceinline__ int packh2(f32x2 v) {
    union { fp16x2 h; int i; } u;
    u.h = __builtin_amdgcn_cvt_pkrtz(v.x, v.y);
    return u.i;
}

// ---------------------------------------------------------------------------
// fp32 -> f16 convert (n multiple of 2048; 8 elems/thread)
// ---------------------------------------------------------------------------
__global__ __launch_bounds__(256) void cvt_kernel(
    const float* __restrict__ src, _Float16* __restrict__ dst)
{
    const int i = (blockIdx.x * 256 + threadIdx.x) * 8;
    float4 a = *(const float4*)(src + i);
    float4 b = *(const float4*)(src + i + 4);
    union { _Float16 h[8]; int4 v; } u;
    u.h[0] = (_Float16)a.x; u.h[1] = (_Float16)a.y;
    u.h[2] = (_Float16)a.z; u.h[3] = (_Float16)a.w;
    u.h[4] = (_Float16)b.x; u.h[5] = (_Float16)b.y;
    u.h[6] = (_Float16)b.z; u.h[7] = (_Float16)b.w;
    *(int4*)(dst + i) = u.v;
}

// 4 weights at once (blockIdx.y selects)
__global__ __launch_bounds__(256) void wcvt_kernel(
    const float* __restrict__ s0, const float* __restrict__ s1,
    const float* __restrict__ s2, const float* __restrict__ s3,
    _Float16* __restrict__ d0, _Float16* __restrict__ d1,
    _Float16* __restrict__ d2, _Float16* __restrict__ d3)
{
    const float* s; _Float16* d;
    switch (blockIdx.y) {
        case 0: s = s0; d = d0; break;
        case 1: s = s1; d = d1; break;
        case 2: s = s2; d = d2; break;
        default: s = s3; d = d3; break;
    }
    const int i = (blockIdx.x * 256 + threadIdx.x) * 8;
    float4 a = *(const float4*)(s + i);
    float4 b = *(const float4*)(s + i + 4);
    union { _Float16 h[8]; int4 v; } u;
    u.h[0] = (_Float16)a.x; u.h[1] = (_Float16)a.y;
    u.h[2] = (_Float16)a.z; u.h[3] = (_Float16)a.w;
    u.h[4] = (_Float16)b.x; u.h[5] = (_Float16)b.y;
    u.h[6] = (_Float16)b.z; u.h[7] = (_Float16)b.w;
    *(int4*)(d + i) = u.v;
}

// ---------------------------------------------------------------------------
// Pure-f16 async MFMA GEMM: C[M,N] = (Ah [+ Al]) [M,K] @ B[N,K]^T (+bias).
// Inputs pre-converted f16. 64x128 tile, BK=64, 4 waves (2x2).
// LDS chunk-major [kc][row][8] so global_load_lds lane->slot is contiguous
// and frag ds_read_b128 is ~2-way bank aliased (free).
// NPROD=1: projections (single product). NPROD=2: + Al·B (Wo GEMM).
// ---------------------------------------------------------------------------
template<int NPROD>
__global__ __launch_bounds__(256) void gemm_f16(
    const _Float16* __restrict__ Ah_g, const _Float16* __restrict__ Al_g,
    const _Float16* __restrict__ B_g, const float* __restrict__ bias,
    float* __restrict__ C, int M, int N, int K, int hasBias)
{
    __shared__ _Float16 Ahs[8][64][8];    //  8 KB
    __shared__ _Float16 Als[8][64][8];    //  8 KB (unused traffic if NPROD=1)
    __shared__ _Float16 Bhs[8][128][8];   // 16 KB

    const int t    = threadIdx.x;
    const int m0   = blockIdx.y * 64;
    const int n0   = blockIdx.x * 128;
    const int lane = t & 63;
    const int w    = t >> 6;
    const int wm   = w >> 1;
    const int wn   = w & 1;
    const int l15  = lane & 15;
    const int quad = lane >> 4;

    f32x4 acc[2][4];
#pragma unroll
    for (int i = 0; i < 2; ++i)
#pragma unroll
        for (int j = 0; j < 4; ++j) acc[i][j] = (f32x4)0.f;

    for (int k0 = 0; k0 < K; k0 += 64) {
        __syncthreads();   // previous chunk's frag reads done
        // staging: wave w handles kc = 2w, 2w+1
#pragma unroll
        for (int i = 0; i < 2; ++i) {
            const int cc = w * 2 + i;
            g2lds16(Ah_g + (size_t)(m0 + lane) * K + k0 + cc * 8, &Ahs[cc][0][0]);
            if (NPROD == 2)
                g2lds16(Al_g + (size_t)(m0 + lane) * K + k0 + cc * 8, &Als[cc][0][0]);
#pragma unroll
            for (int half = 0; half < 2; ++half)
                g2lds16(B_g + (size_t)(n0 + half * 64 + lane) * K + k0 + cc * 8,
                        &Bhs[cc][half * 64][0]);
        }
        __syncthreads();   // vmcnt drained

#pragma unroll
        for (int kh = 0; kh < 2; ++kh) {
            f16x8 ah[2], bh[4];
#pragma unroll
            for (int tm = 0; tm < 2; ++tm)
                ah[tm] = *(const f16x8*)&Ahs[kh * 4 + quad][wm * 32 + tm * 16 + l15][0];
#pragma unroll
            for (int tn = 0; tn < 4; ++tn)
                bh[tn] = *(const f16x8*)&Bhs[kh * 4 + quad][wn * 64 + tn * 16 + l15][0];
#pragma unroll
            for (int tm = 0; tm < 2; ++tm)
#pragma unroll
                for (int tn = 0; tn < 4; ++tn)
                    acc[tm][tn] = __builtin_amdgcn_mfma_f32_16x16x32_f16(
                        ah[tm], bh[tn], acc[tm][tn], 0, 0, 0);
            if (NPROD == 2) {
                f16x8 al[2];
#pragma unroll
                for (int tm = 0; tm < 2; ++tm)
                    al[tm] = *(const f16x8*)&Als[kh * 4 + quad][wm * 32 + tm * 16 + l15][0];
#pragma unroll
                for (int tm = 0; tm < 2; ++tm)
#pragma unroll
                    for (int tn = 0; tn < 4; ++tn)
                        acc[tm][tn] = __builtin_amdgcn_mfma_f32_16x16x32_f16(
                            al[tm], bh[tn], acc[tm][tn], 0, 0, 0);
            }
        }
    }

#pragma unroll
    for (int tm = 0; tm < 2; ++tm)
#pragma unroll
        for (int tn = 0; tn < 4; ++tn) {
            const int col  = n0 + wn * 64 + tn * 16 + l15;
            const float bv = hasBias ? bias[col] : 0.f;
            const int rowb = m0 + wm * 32 + tm * 16 + quad * 4;
#pragma unroll
            for (int r = 0; r < 4; ++r)
                C[(size_t)(rowb + r) * N + col] = acc[tm][tn][r] + bv;
        }
}

// ---------------------------------------------------------------------------
// Normalize each 64-wide head segment; emit f16 at [b][h][t][dk].
// ---------------------------------------------------------------------------
__global__ __launch_bounds__(256) void norm_kernel(
    const float* __restrict__ X, _Float16* __restrict__ H)
{
    const int seg  = blockIdx.x * 4 + (threadIdx.x >> 6);
    const int lane = threadIdx.x & 63;
    const int row  = seg >> 4;   // b*T + t
    const int h    = seg & 15;
    float v = X[(size_t)row * DD + h * DK + lane];
    float s = v * v;
    s += __shfl_xor(s, 1);
    s += __shfl_xor(s, 2);
    s += __shfl_xor(s, 4);
    s += __shfl_xor(s, 8);
    s += __shfl_xor(s, 16);
    s += __shfl_xor(s, 32);
    float n = sqrtf(s);
    float vn = v / fmaxf(n, 1e-12f);
    const int b  = row >> 11;
    const int tt = row & 2047;
    H[((size_t)(b * HH + h) * TT + tt) * DK + lane] = (_Float16)vn;
}

// ---------------------------------------------------------------------------
// V -> f16 transposed [b][h][d][T].
// ---------------------------------------------------------------------------
__global__ __launch_bounds__(256) void vtrans_kernel(
    const float* __restrict__ V0, _Float16* __restrict__ Vt)
{
    __shared__ _Float16 Vtmp[64][72];
    const int t  = threadIdx.x;
    const int t0 = blockIdx.x * 64;
    const int h  = blockIdx.y;
    const int b  = blockIdx.z;

    {
        const int i  = t >> 2;            // token row 0..63
        const int jc = (t & 3) * 16;      // dim chunk
        const float* src = V0 + (size_t)(b * TT + t0 + i) * DD + h * DK + jc;
#pragma unroll
        for (int c = 0; c < 4; ++c) {
            float4 v = *(const float4*)(src + c * 4);
            Vtmp[jc + c * 4 + 0][i] = (_Float16)v.x;
            Vtmp[jc + c * 4 + 1][i] = (_Float16)v.y;
            Vtmp[jc + c * 4 + 2][i] = (_Float16)v.z;
            Vtmp[jc + c * 4 + 3][i] = (_Float16)v.w;
        }
    }
    __syncthreads();
    {
        const int d  = t >> 2;
        const int kc = (t & 3) * 16;
        _Float16* dst = Vt + ((size_t)((b * HH + h) * DK + d)) * TT + t0 + kc;
        *(int4*)(dst)     = *(const int4*)&Vtmp[d][kc];
        *(int4*)(dst + 8) = *(const int4*)&Vtmp[d][kc + 8];
    }
}

// ---------------------------------------------------------------------------
// MFMA angular attention v5 — all-f16. Grid (T/64, H, B), 256 threads.
// Single-product f16 QK^T (sim err sigma ~2.5e-5, better than bf16 hi/lo).
// Phase A: wave w -> S^T for its 32 keys x 64 q; poly transform; f16 W via
// v_cvt_pkrtz. Phase B: wave w -> full O[16q x 64d] over 128 keys.
// Epilogue emits O split hi/lo f16 for the async Wo GEMM.
// LDS ~60.4 KB -> 2 blocks/CU.
// ---------------------------------------------------------------------------
__global__ __launch_bounds__(256) void attn_kernel(
    const _Float16* __restrict__ Qh_g, const _Float16* __restrict__ Kh_g,
    const _Float16* __restrict__ Vt_g,
    _Float16* __restrict__ Oh, _Float16* __restrict__ Ol)
{
    __shared__ _Float16 Khs[8][128][8];  // [dk-chunk][key][8]  16384 B
    __shared__ _Float16 Vts[16][64][8];  // [key-chunk][d][8]   16384 B
    __shared__ _Float16 Ws[64][136];     // [q][key]            17408 B
    __shared__ _Float16 Qhs[64][72];     // [q][dk]              9216 B
    __shared__ float Rbuf[4][64];        //                      1024 B
    __shared__ float Rfin[64];           //                       256 B

    const int t    = threadIdx.x;
    const int lane = t & 63;
    const int w    = t >> 6;
    const int l15  = lane & 15;
    const int quad = lane >> 4;
    const int q0   = blockIdx.x * 64;
    const int h    = blockIdx.y;
    const int b    = blockIdx.z;
    const size_t bh = (size_t)(b * HH + h);

    // stage Q into LDS (once): 64 rows x 64 f16
    {
        const int row = t >> 2;
        const int col = (t & 3) * 16;
        const _Float16* sq = Qh_g + (bh * TT + q0 + row) * DK + col;
        *(int4*)&Qhs[row][col]     = *(const int4*)(sq);
        *(int4*)&Qhs[row][col + 8] = *(const int4*)(sq + 8);
    }

    f32x4 acc[4];    // O[16q x 64d] for q-tile w
#pragma unroll
    for (int j = 0; j < 4; ++j) acc[j] = (f32x4)0.f;
    f32x2 rs2[4];
#pragma unroll
    for (int j = 0; j < 4; ++j) rs2[j] = (f32x2)0.f;

    const _Float16* kh_g = Kh_g + bh * TT * DK;
    const _Float16* vt_g = Vt_g + bh * (size_t)DK * TT;

    for (int k0 = 0; k0 < TT; k0 += KT) {
        __syncthreads();   // prev tile fully consumed (1st iter: Q staged)

        // async staging: K 16 KB + V 16 KB, wave-partitioned
#pragma unroll
        for (int i = 0; i < 2; ++i) {
            const int cc = w * 2 + i;
#pragma unroll
            for (int half = 0; half < 2; ++half)
                g2lds16(kh_g + (size_t)(k0 + half * 64 + lane) * DK + cc * 8,
                        &Khs[cc][half * 64][0]);
        }
#pragma unroll
        for (int j = 0; j < 4; ++j) {
            const int kc = w * 4 + j;
            g2lds16(vt_g + (size_t)lane * TT + k0 + kc * 8, &Vts[kc][0][0]);
        }
        __syncthreads();   // vmcnt drained -> Khs/Vts valid

        // K frags for wave's 32 keys (hoisted across qt)
        f16x8 kf[2][2];    // [s][mt]
#pragma unroll
        for (int s = 0; s < 2; ++s)
#pragma unroll
            for (int mt = 0; mt < 2; ++mt)
                kf[s][mt] = *(const f16x8*)&Khs[s * 4 + quad][w * 32 + mt * 16 + l15][0];

        // Phase A: S^T for wave's 32 keys x 64 q, transform, write Ws
#pragma unroll
        for (int qt = 0; qt < 4; ++qt) {
            f32x4 c_[2];
            c_[0] = (f32x4)0.f;
            c_[1] = (f32x4)0.f;
#pragma unroll
            for (int s = 0; s < 2; ++s) {
                f16x8 qh = *(const f16x8*)&Qhs[qt * 16 + l15][s * 32 + quad * 8];
#pragma unroll
                for (int mt = 0; mt < 2; ++mt)
                    c_[mt] = __builtin_amdgcn_mfma_f32_16x16x32_f16(
                        kf[s][mt], qh, c_[mt], 0, 0, 0);
            }
#pragma unroll
            for (int mt = 0; mt < 2; ++mt) {
                f32x2 p01, p23;
                p01.x = c_[mt][0]; p01.y = c_[mt][1];
                p23.x = c_[mt][2]; p23.y = c_[mt][3];
                f32x2 w01 = w8pair(p01, rs2[qt]);
                f32x2 w23 = w8pair(p23, rs2[qt]);
                int2 pk;
                pk.x = packh2(w01);
                pk.y = packh2(w23);
                *(int2*)&Ws[qt * 16 + l15][w * 32 + mt * 16 + quad * 4] = pk;
            }
        }
        __syncthreads();   // Ws complete across waves

        // Phase B: PV for q-tile w over all 128 keys
#pragma unroll
        for (int kstep = 0; kstep < 4; ++kstep) {
            f16x8 av = *(const f16x8*)&Ws[16 * w + l15][kstep * 32 + quad * 8];
#pragma unroll
            for (int nd = 0; nd < 4; ++nd) {
                f16x8 bv = *(const f16x8*)&Vts[kstep * 4 + quad][nd * 16 + l15][0];
                acc[nd] = __builtin_amdgcn_mfma_f32_16x16x32_f16(
                    av, bv, acc[nd], 0, 0, 0);
            }
        }
    }

    // rowsum: rs2[qt] covers q = qt*16+l15 over wave's keys
#pragma unroll
    for (int qt = 0; qt < 4; ++qt) {
        float p = rs2[qt].x + rs2[qt].y;
        p += __shfl_xor(p, 16);
        p += __shfl_xor(p, 32);
        if (quad == 0) Rbuf[w][qt * 16 + l15] = p;
    }
    __syncthreads();
    if (t < 64) {
        float s = Rbuf[0][t] + Rbuf[1][t] + Rbuf[2][t] + Rbuf[3][t];
        Rfin[t] = 1.f / (s + 1e-6f);
    }
    __syncthreads();

    // store: O split hi/lo f16 (feeds the 2-product Wo GEMM)
#pragma unroll
    for (int r = 0; r < 4; ++r) {
        const int q = 16 * w + quad * 4 + r;
        const float inv = Rfin[q];
        const size_t base = (size_t)(b * TT + q0 + q) * DD + h * DK + l15;
#pragma unroll
        for (int nd = 0; nd < 4; ++nd) {
            float v = acc[nd][r] * inv;
            _Float16 hv = (_Float16)v;
            Oh[base + nd * 16] = hv;
            Ol[base + nd * 16] = (_Float16)(v - (float)hv);
        }
    }
}

// ---------------------------------------------------------------------------
extern "C" void kernel_launch(void* const* d_in, const int* in_sizes, int n_in,
                              void* d_out, int out_size, void* d_ws, size_t ws_size,
                              hipStream_t stream)
{
    const float* x  = (const float*)d_in[0];
    const float* Wq = (const float*)d_in[1];
    const float* Wk = (const float*)d_in[2];
    const float* Wv = (const float*)d_in[3];
    const float* Wo = (const float*)d_in[4];
    const float* bo = (const float*)d_in[5];
    float* out = (float*)d_out;

    const int M = BB * TT;   // 4096
    const int N = DD;
    const int K = DD;

    const size_t MB = 1024 * 1024;
    char* ws = (char*)d_ws;
    // [0,8):   xh f16                -> Kh f16 (after projections)
    // [8,16):  Wqh,Wkh,Wvh,Woh f16 (2 MB each; Woh persists)
    // [16,32): Q0 fp32               -> Oh [16,24) + Ol [24,32) (after norm Q)
    // [32,48): K0 fp32               -> Qh [32,40) + Vt [40,48) (after norm K)
    // [48,64): V0 fp32
    _Float16* xh  = (_Float16*)(ws);
    _Float16* Wqh = (_Float16*)(ws + 8 * MB);
    _Float16* Wkh = (_Float16*)(ws + 10 * MB);
    _Float16* Wvh = (_Float16*)(ws + 12 * MB);
    _Float16* Woh = (_Float16*)(ws + 14 * MB);
    float*    Q0  = (float*)(ws + 16 * MB);
    float*    K0  = (float*)(ws + 32 * MB);
    float*    V0  = (float*)(ws + 48 * MB);
    _Float16* Kh  = (_Float16*)(ws);
    _Float16* Qh  = (_Float16*)(ws + 32 * MB);
    _Float16* Vt  = (_Float16*)(ws + 40 * MB);
    _Float16* Oh  = (_Float16*)(ws + 16 * MB);
    _Float16* Ol  = (_Float16*)(ws + 24 * MB);

    dim3 gB(256);
    dim3 gGemm(N / 128, M / 64);   // (8, 64)

    // convert inputs to f16
    cvt_kernel<<<(M * DD) / 2048, gB, 0, stream>>>(x, xh);
    wcvt_kernel<<<dim3((DD * DD) / 2048, 4), gB, 0, stream>>>(
        Wq, Wk, Wv, Wo, Wqh, Wkh, Wvh, Woh);

    // projections (single-product f16)
    gemm_f16<1><<<gGemm, gB, 0, stream>>>(xh, nullptr, Wqh, nullptr, Q0, M, N, K, 0);
    gemm_f16<1><<<gGemm, gB, 0, stream>>>(xh, nullptr, Wkh, nullptr, K0, M, N, K, 0);
    gemm_f16<1><<<gGemm, gB, 0, stream>>>(xh, nullptr, Wvh, nullptr, V0, M, N, K, 0);

    // normalize + layout transforms (buffer reuse is stream-ordered)
    const int nSeg = M * HH;  // 65536
    norm_kernel<<<nSeg / 4, gB, 0, stream>>>(K0, Kh);   // K0 dead after
    norm_kernel<<<nSeg / 4, gB, 0, stream>>>(Q0, Qh);   // writes into old K0
    vtrans_kernel<<<dim3(TT / 64, HH, BB), gB, 0, stream>>>(V0, Vt);

    // fused angular attention -> O split f16 hi/lo (into old Q0 region)
    attn_kernel<<<dim3(TT / 64, HH, BB), gB, 0, stream>>>(Qh, Kh, Vt, Oh, Ol);

    // output projection: (Oh + Ol) @ Woh^T + bo
    gemm_f16<2><<<gGemm, gB, 0, stream>>>(Oh, Ol, Woh, bo, out, M, N, K, 1);
}